// Round 11
// baseline (250.166 us; speedup 1.0000x reference)
//
#include <hip/hip_runtime.h>
#include <hip/hip_cooperative_groups.h>
#include <hip/hip_bf16.h>
#include <math.h>
#include <cstdint>

namespace cg = cooperative_groups;

#define NUSER 16384   // B*U
#define BB    64
#define UU    256
#define SSLOT 64
#define HD    256
#define KTOT  320
#define DEGS  8
#define DEGU  16
#define SMEMB 53248   // max static LDS across phases (< 64 KB for coop validation)

typedef __attribute__((ext_vector_type(8))) short short8;
typedef __attribute__((ext_vector_type(4))) float f32x4;

static __device__ __forceinline__ __hip_bfloat16 f2b(float x) { return __float2bfloat16(x); }
static __device__ __forceinline__ unsigned pack2(float x, float y) {
  union { __hip_bfloat16 h[2]; unsigned u; } cv;
  cv.h[0] = f2b(x); cv.h[1] = f2b(y);
  return cv.u;
}

struct MegaArgs {
  const int *dst_u2s, *dst_u2u;
  const float *xu, *xs;
  const float *oW1, *ob1, *oW2, *ob2, *oW3, *ob3;
  const float *sW1, *sb1, *sW2, *sb2, *sW3, *sb3;
  unsigned long long* connS;
  unsigned* MSUW;
  __hip_bfloat16 *PQT_o, *PQT_s, *h1o, *h1s, *W2T_o, *W2T_s, *W3T_s;
  float* out;
};

// ================= Phase A+B: masks, weight transposes, layer-1 -> PQT ======
static __device__ void phaseAB(const MegaArgs& a, int blk, int t) {
  if (blk < 64) {
    const int u = blk * 256 + t;
    unsigned long long ms = 0ull;
    #pragma unroll
    for (int i = 0; i < DEGS; ++i) ms |= 1ull << (a.dst_u2s[u * DEGS + i] & 63);
    a.connS[u] = ms;
    unsigned long long m0 = 0, m1 = 0, m2 = 0, m3 = 0;
    #pragma unroll
    for (int i = 0; i < DEGU; ++i) {
      int slot = a.dst_u2u[u * DEGU + i] & 255;
      unsigned long long bit = 1ull << (slot & 63);
      int w = slot >> 6;
      if (w == 0) m0 |= bit; else if (w == 1) m1 |= bit;
      else if (w == 2) m2 |= bit; else m3 |= bit;
    }
    uint2* mw2 = (uint2*)(a.MSUW + (size_t)u * 10);
    mw2[0] = make_uint2((unsigned)ms, (unsigned)(ms >> 32));
    mw2[1] = make_uint2((unsigned)m0, (unsigned)(m0 >> 32));
    mw2[2] = make_uint2((unsigned)m1, (unsigned)(m1 >> 32));
    mw2[3] = make_uint2((unsigned)m2, (unsigned)(m2 >> 32));
    mw2[4] = make_uint2((unsigned)m3, (unsigned)(m3 >> 32));
    a.W3T_s[blk * HD + t] = f2b(a.sW3[t * SSLOT + blk]);
  }
  a.W2T_o[blk * HD + t] = f2b(a.oW2[t * HD + blk]);
  a.W2T_s[blk * HD + t] = f2b(a.sW2[t * HD + blk]);

  for (int unit = blk; unit < 320; unit += 256) {
    const int sg = unit >> 6, ng = unit & 63;
    const int s = t & 63, ni = t >> 6;
    const int n = ng * 4 + ni;
    const int rbase = (sg == 0) ? s * 16 : 1024 + ((sg - 1) * 64 + s) * 16;
    float wo[16], wsv[16];
    #pragma unroll
    for (int d = 0; d < 16; ++d) {
      wo[d]  = a.oW1[(rbase + d) * HD + n];
      wsv[d] = a.sW1[(rbase + d) * HD + n];
    }
    const float* xbase = (sg == 0) ? a.xs : (a.xu + (size_t)(sg - 1) * 64 * 16);
    const int xstride = (sg == 0) ? 1024 : 4096;
    const int kk = sg * 64 + s;
    for (int b = 0; b < BB; ++b) {
      const float4* xp = (const float4*)(xbase + (size_t)b * xstride + s * 16);
      float4 x0 = xp[0], x1 = xp[1], x2 = xp[2], x3 = xp[3];
      float ao, as;
      ao  = x0.x * wo[0];  as  = x0.x * wsv[0];
      ao = fmaf(x0.y, wo[1], ao);  as = fmaf(x0.y, wsv[1], as);
      ao = fmaf(x0.z, wo[2], ao);  as = fmaf(x0.z, wsv[2], as);
      ao = fmaf(x0.w, wo[3], ao);  as = fmaf(x0.w, wsv[3], as);
      ao = fmaf(x1.x, wo[4], ao);  as = fmaf(x1.x, wsv[4], as);
      ao = fmaf(x1.y, wo[5], ao);  as = fmaf(x1.y, wsv[5], as);
      ao = fmaf(x1.z, wo[6], ao);  as = fmaf(x1.z, wsv[6], as);
      ao = fmaf(x1.w, wo[7], ao);  as = fmaf(x1.w, wsv[7], as);
      ao = fmaf(x2.x, wo[8], ao);  as = fmaf(x2.x, wsv[8], as);
      ao = fmaf(x2.y, wo[9], ao);  as = fmaf(x2.y, wsv[9], as);
      ao = fmaf(x2.z, wo[10], ao); as = fmaf(x2.z, wsv[10], as);
      ao = fmaf(x2.w, wo[11], ao); as = fmaf(x2.w, wsv[11], as);
      ao = fmaf(x3.x, wo[12], ao); as = fmaf(x3.x, wsv[12], as);
      ao = fmaf(x3.y, wo[13], ao); as = fmaf(x3.y, wsv[13], as);
      ao = fmaf(x3.z, wo[14], ao); as = fmaf(x3.z, wsv[14], as);
      ao = fmaf(x3.w, wo[15], ao); as = fmaf(x3.w, wsv[15], as);
      const size_t off = (size_t)(b * 256 + n) * KTOT + kk;
      a.PQT_o[off] = f2b(ao);
      a.PQT_s[off] = f2b(as);
    }
  }
}

// ================= Phase C: h1 via mask-MFMA, k-chunked 53 KB LDS ==========
static __device__ void phaseC(const MegaArgs& a, int blk, int t, char* smem) {
  const int b = blk >> 2, mlp = (blk >> 1) & 1, nh = blk & 1;
  const int n0 = nh * 128;
  short* pan = (short*)smem;                   // [128][168] (43008 B), no swizzle
  unsigned* mskL = (unsigned*)(smem + 43008);  // 2560 u32 (10240 B)
  const __hip_bfloat16* PQT = mlp ? a.PQT_s : a.PQT_o;
  const float* b1 = mlp ? a.sb1 : a.ob1;
  __hip_bfloat16* h1 = mlp ? a.h1s : a.h1o;

  {
    const uint2* g2 = (const uint2*)(a.MSUW + (size_t)b * 2560);
    uint2* l2 = (uint2*)mskL;
    #pragma unroll
    for (int i = 0; i < 5; ++i) l2[t + 256 * i] = g2[t + 256 * i];
  }
  const int lane = t & 63, w = t >> 6;
  const int lo = lane & 15, hi = lane >> 4;
  f32x4 acc[4][8] = {};
  for (int kc = 0; kc < 2; ++kc) {
    if (kc) __syncthreads();                   // protect pan reuse
    {
      const int r = t >> 1, c4 = t & 1;
      const __hip_bfloat16* src = PQT + (size_t)(b * 256 + n0 + r) * KTOT + kc * 160;
      #pragma unroll
      for (int i = 0; i < 10; ++i) {
        int cc = c4 + 2 * i;
        *(short8*)&pan[r * 168 + cc * 8] = *(const short8*)(src + cc * 8);
      }
    }
    __syncthreads();
    #pragma unroll
    for (int kt2 = 0; kt2 < 5; ++kt2) {
      const int kt = kc * 5 + kt2;
      short8 af[4], bf[8];
      #pragma unroll
      for (int rb = 0; rb < 4; ++rb) {
        int ul = w * 64 + rb * 16 + lo;
        unsigned m = mskL[ul * 10 + kt];
        unsigned by = (m >> (hi * 8)) & 0xFFu;
        union { unsigned u[4]; short8 s; } cv;
        cv.u[0] = ((by & 1u)  ? 0x3F80u : 0u) | ((by & 2u)   ? 0x3F800000u : 0u);
        cv.u[1] = ((by & 4u)  ? 0x3F80u : 0u) | ((by & 8u)   ? 0x3F800000u : 0u);
        cv.u[2] = ((by & 16u) ? 0x3F80u : 0u) | ((by & 32u)  ? 0x3F800000u : 0u);
        cv.u[3] = ((by & 64u) ? 0x3F80u : 0u) | ((by & 128u) ? 0x3F800000u : 0u);
        af[rb] = cv.s;
      }
      #pragma unroll
      for (int cb = 0; cb < 8; ++cb) {
        int n = cb * 16 + lo;
        bf[cb] = *(const short8*)&pan[n * 168 + (kt2 * 4 + hi) * 8];
      }
      #pragma unroll
      for (int rb = 0; rb < 4; ++rb)
        #pragma unroll
        for (int cb = 0; cb < 8; ++cb)
          acc[rb][cb] = __builtin_amdgcn_mfma_f32_16x16x32_bf16(af[rb], bf[cb], acc[rb][cb], 0, 0, 0);
    }
  }
  #pragma unroll
  for (int cb = 0; cb < 8; ++cb) {
    int n = cb * 16 + lo;
    float bv = b1[n0 + n];
    #pragma unroll
    for (int rb = 0; rb < 4; ++rb) {
      #pragma unroll
      for (int j = 0; j < 4; ++j) {
        int u = b * 256 + w * 64 + rb * 16 + hi * 4 + j;
        h1[(size_t)u * HD + n0 + n] = f2b(fmaxf(acc[rb][cb][j] + bv, 0.f));
      }
    }
  }
}

// ================= Phase D: layer-2 GEMM + heads ===========================
static __device__ void phaseD(const MegaArgs& a, int blk, int t, char* smem) {
  short* As = (short*)smem;               // 32 x 256 swizzled (16 KB)
  short* Bs = (short*)(smem + 16384);     // 256 x 72 padded (36 KB)
  float* part = (float*)smem;             // alias
  const int lane = t & 63, wid = t >> 6;
  const int lo = lane & 15, hi = lane >> 4;

  for (int un = 0; un < 4; ++un) {
    const int unit = un * 256 + blk;
    const int mlp = unit >> 9;
    const int u0 = (unit & 511) * 32;
    const __hip_bfloat16* A   = mlp ? a.h1s : a.h1o;
    const __hip_bfloat16* W2T = mlp ? a.W2T_s : a.W2T_o;
    const float* b2 = mlp ? a.sb2 : a.ob2;

    if (un) __syncthreads();
    #pragma unroll
    for (int i = 0; i < 4; ++i) {
      int c = t + i * 256;
      int row = c >> 5, cc = c & 31;
      *(short8*)&As[row * 256 + (cc ^ (row & 7)) * 8] =
          *(const short8*)(A + (size_t)(u0 + row) * HD + cc * 8);
    }
    __syncthreads();

    f32x4 acc2[2][4] = {};
    for (int ks = 0; ks < 8; ++ks) {
      if (ks) __syncthreads();
      #pragma unroll
      for (int i = 0; i < 4; ++i) {
        int c = t + i * 256;
        int n = c >> 2, kc = c & 3;
        *(short8*)&Bs[n * 72 + kc * 8] =
            *(const short8*)(W2T + (size_t)n * HD + ks * 32 + kc * 8);
      }
      __syncthreads();
      short8 af[2], bf[4];
      #pragma unroll
      for (int rb = 0; rb < 2; ++rb) {
        int row = rb * 16 + lo;
        int ca = ks * 4 + hi;
        af[rb] = *(const short8*)&As[row * 256 + (ca ^ (row & 7)) * 8];
      }
      #pragma unroll
      for (int cb = 0; cb < 4; ++cb) {
        int n = wid * 64 + cb * 16 + lo;
        bf[cb] = *(const short8*)&Bs[n * 72 + hi * 8];
      }
      #pragma unroll
      for (int rb = 0; rb < 2; ++rb)
        #pragma unroll
        for (int cb = 0; cb < 4; ++cb)
          acc2[rb][cb] = __builtin_amdgcn_mfma_f32_16x16x32_bf16(af[rb], bf[cb], acc2[rb][cb], 0, 0, 0);
    }
    __syncthreads();

    if (mlp == 0) {
      float p0[2][4] = {}, p1[2][4] = {};
      #pragma unroll
      for (int cb = 0; cb < 4; ++cb) {
        int n = wid * 64 + cb * 16 + lo;
        float bs = b2[n], w0 = a.oW3[2 * n], w1 = a.oW3[2 * n + 1];
        #pragma unroll
        for (int rb = 0; rb < 2; ++rb)
          #pragma unroll
          for (int j = 0; j < 4; ++j) {
            float sig = 1.0f / (1.0f + __expf(-(acc2[rb][cb][j] + bs)));
            p0[rb][j] = fmaf(sig, w0, p0[rb][j]);
            p1[rb][j] = fmaf(sig, w1, p1[rb][j]);
          }
      }
      #pragma unroll
      for (int rb = 0; rb < 2; ++rb)
        #pragma unroll
        for (int j = 0; j < 4; ++j) {
          #pragma unroll
          for (int off = 1; off < 16; off <<= 1) {
            p0[rb][j] += __shfl_xor(p0[rb][j], off, 64);
            p1[rb][j] += __shfl_xor(p1[rb][j], off, 64);
          }
          if (lo == 0) {
            int row = rb * 16 + hi * 4 + j;
            part[wid * 64 + row * 2 + 0] = p0[rb][j];
            part[wid * 64 + row * 2 + 1] = p1[rb][j];
          }
        }
      __syncthreads();
      if (t < 32) {
        float q0 = part[t * 2] + part[64 + t * 2] + part[128 + t * 2] + part[192 + t * 2] + a.ob3[0];
        float q1 = part[t * 2 + 1] + part[64 + t * 2 + 1] + part[128 + t * 2 + 1] + part[192 + t * 2 + 1] + a.ob3[1];
        float m2 = fmaxf(q0, q1);
        float e0 = __expf(q0 - m2), e1 = __expf(q1 - m2);
        float iv = 1.0f / (e0 + e1);
        float2 r; r.x = e0 * iv; r.y = e1 * iv;
        *(float2*)(a.out + (size_t)(u0 + t) * 2) = r;
      }
    } else {
      short* sel = As;
      #pragma unroll
      for (int cb = 0; cb < 4; ++cb) {
        int n = wid * 64 + cb * 16 + lo;
        float bs = b2[n];
        #pragma unroll
        for (int rb = 0; rb < 2; ++rb)
          #pragma unroll
          for (int j = 0; j < 4; ++j) {
            int row = rb * 16 + hi * 4 + j;
            float sig = 1.0f / (1.0f + __expf(-(acc2[rb][cb][j] + bs)));
            sel[row * 256 + ((n >> 3) ^ (row & 7)) * 8 + (n & 7)] = (short)pack2(sig, 0.f);
          }
      }
      __syncthreads();
      if (wid < 2) {
        f32x4 acc3[4] = {};
        #pragma unroll
        for (int ks = 0; ks < 8; ++ks) {
          int row = wid * 16 + lo;
          int ca = ks * 4 + hi;
          short8 af = *(const short8*)&sel[row * 256 + (ca ^ (row & 7)) * 8];
          #pragma unroll
          for (int cb = 0; cb < 4; ++cb) {
            short8 bf = *(const short8*)(a.W3T_s + (size_t)(cb * 16 + lo) * HD + ks * 32 + hi * 8);
            acc3[cb] = __builtin_amdgcn_mfma_f32_16x16x32_bf16(af, bf, acc3[cb], 0, 0, 0);
          }
        }
        float sb3n[4];
        #pragma unroll
        for (int cb = 0; cb < 4; ++cb) sb3n[cb] = a.sb3[cb * 16 + lo];
        const int ubase = u0 + wid * 16 + hi * 4;
        #pragma unroll
        for (int j = 0; j < 4; ++j) {
          unsigned long long m = a.connS[ubase + j];
          float v[4]; bool ok[4];
          float mx = -INFINITY;
          #pragma unroll
          for (int cb = 0; cb < 4; ++cb) {
            int n = cb * 16 + lo;
            ok[cb] = (m >> n) & 1ull;
            v[cb] = ok[cb] ? (acc3[cb][j] + sb3n[cb]) : -INFINITY;
            mx = fmaxf(mx, v[cb]);
          }
          #pragma unroll
          for (int off = 1; off < 16; off <<= 1) mx = fmaxf(mx, __shfl_xor(mx, off, 64));
          float e[4], ssum = 0.f;
          #pragma unroll
          for (int cb = 0; cb < 4; ++cb) {
            e[cb] = ok[cb] ? __expf(v[cb] - mx) : 0.f;
            ssum += e[cb];
          }
          #pragma unroll
          for (int off = 1; off < 16; off <<= 1) ssum += __shfl_xor(ssum, off, 64);
          float iv = 1.0f / ssum;
          #pragma unroll
          for (int cb = 0; cb < 4; ++cb) {
            int n = cb * 16 + lo;
            a.out[(size_t)NUSER * 2 + (size_t)(ubase + j) * SSLOT + n] = e[cb] * iv;
          }
        }
      }
    }
  }
}

// ================= kernels =================================================
__global__ __launch_bounds__(256) void k_mega(MegaArgs a) {
  __shared__ __align__(16) char smem[SMEMB];
  cg::grid_group grid = cg::this_grid();
  phaseAB(a, blockIdx.x, threadIdx.x);
  __threadfence();
  grid.sync();
  phaseC(a, blockIdx.x, threadIdx.x, smem);
  __threadfence();
  grid.sync();
  phaseD(a, blockIdx.x, threadIdx.x, smem);
}

__global__ __launch_bounds__(256) void k_p1(MegaArgs a) {
  phaseAB(a, blockIdx.x, threadIdx.x);
}
__global__ __launch_bounds__(256) void k_p2(MegaArgs a) {
  __shared__ __align__(16) char smem[SMEMB];
  phaseC(a, blockIdx.x, threadIdx.x, smem);
}
__global__ __launch_bounds__(256) void k_p3(MegaArgs a) {
  __shared__ __align__(16) char smem[SMEMB];
  phaseD(a, blockIdx.x, threadIdx.x, smem);
}

// ---------------------------------------------------------------------------
extern "C" void kernel_launch(void* const* d_in, const int* in_sizes, int n_in,
                              void* d_out, int out_size, void* d_ws, size_t ws_size,
                              hipStream_t stream) {
  char* ws = (char*)d_ws;
  MegaArgs ha;
  ha.dst_u2s = (const int*)d_in[3];
  ha.dst_u2u = (const int*)d_in[5];
  ha.xu  = (const float*)d_in[0];
  ha.xs  = (const float*)d_in[1];
  ha.oW1 = (const float*)d_in[6];  ha.ob1 = (const float*)d_in[7];
  ha.oW2 = (const float*)d_in[8];  ha.ob2 = (const float*)d_in[9];
  ha.oW3 = (const float*)d_in[10]; ha.ob3 = (const float*)d_in[11];
  ha.sW1 = (const float*)d_in[12]; ha.sb1 = (const float*)d_in[13];
  ha.sW2 = (const float*)d_in[14]; ha.sb2 = (const float*)d_in[15];
  ha.sW3 = (const float*)d_in[16]; ha.sb3 = (const float*)d_in[17];
  ha.connS = (unsigned long long*)(ws + 0);              // 128 KB
  ha.MSUW  = (unsigned*)(ws + 131072);                   // 640 KB
  ha.PQT_o = (__hip_bfloat16*)(ws + 786432);             // 10 MB
  ha.PQT_s = (__hip_bfloat16*)(ws + 11272192);           // 10 MB
  ha.h1o   = (__hip_bfloat16*)(ws + 21757952);           // 8 MB
  ha.h1s   = (__hip_bfloat16*)(ws + 30146560);           // 8 MB
  ha.W2T_o = (__hip_bfloat16*)(ws + 38535168);           // 128 KB
  ha.W2T_s = (__hip_bfloat16*)(ws + 38666240);           // 128 KB
  ha.W3T_s = (__hip_bfloat16*)(ws + 38797312);           // 32 KB
  ha.out = (float*)d_out;

  void* params[] = { &ha };
  hipError_t err = hipLaunchCooperativeKernel((void*)k_mega, dim3(256), dim3(256),
                                              params, 0, stream);
  if (err != hipSuccess) {
    // deterministic fallback: same phases as ordinary dependent launches
    k_p1<<<256, 256, 0, stream>>>(ha);
    k_p2<<<256, 256, 0, stream>>>(ha);
    k_p3<<<256, 256, 0, stream>>>(ha);
  }
}

// Round 12
// 161.569 us; speedup vs baseline: 1.5484x; 1.5484x over previous
//
#include <hip/hip_runtime.h>
#include <hip/hip_bf16.h>
#include <math.h>
#include <cstdint>

#define NUSER 16384   // B*U
#define BB    64
#define UU    256
#define SSLOT 64
#define HD    256
#define KTOT  320
#define DEGS  8
#define DEGU  16

typedef __attribute__((ext_vector_type(8))) short short8;
typedef __attribute__((ext_vector_type(4))) float f32x4;

static __device__ __forceinline__ __hip_bfloat16 f2b(float x) { return __float2bfloat16(x); }
static __device__ __forceinline__ unsigned pack2(float x, float y) {
  union { __hip_bfloat16 h[2]; unsigned u; } cv;
  cv.h[0] = f2b(x); cv.h[1] = f2b(y);
  return cv.u;
}

// ---------------------------------------------------------------------------
// K1: y==0: masks+MSUW (x<64) and weight transposes (all x).
//     y>=1: layer-1 with DIRECT transposed PQT write (8 batches per block).
// grid (320, 9) = 2880 blocks.
// ---------------------------------------------------------------------------
__global__ __launch_bounds__(256) void k_p1(
    const int* __restrict__ dst_u2s, const int* __restrict__ dst_u2u,
    const float* __restrict__ oW2, const float* __restrict__ sW2,
    const float* __restrict__ sW3,
    const float* __restrict__ xu, const float* __restrict__ xs,
    const float* __restrict__ oW1, const float* __restrict__ sW1,
    unsigned long long* __restrict__ connS, unsigned* __restrict__ MSUW,
    __hip_bfloat16* __restrict__ W2T_o, __hip_bfloat16* __restrict__ W2T_s,
    __hip_bfloat16* __restrict__ W3T_s,
    __hip_bfloat16* __restrict__ PQT_o, __hip_bfloat16* __restrict__ PQT_s) {
  const int t = threadIdx.x;
  const int x = blockIdx.x;
  if (blockIdx.y == 0) {
    if (x < 64) {
      const int u = x * 256 + t;
      unsigned long long ms = 0ull;
      #pragma unroll
      for (int i = 0; i < DEGS; ++i) ms |= 1ull << (dst_u2s[u * DEGS + i] & 63);
      connS[u] = ms;
      unsigned long long m0 = 0, m1 = 0, m2 = 0, m3 = 0;
      #pragma unroll
      for (int i = 0; i < DEGU; ++i) {
        int slot = dst_u2u[u * DEGU + i] & 255;
        unsigned long long bit = 1ull << (slot & 63);
        int w = slot >> 6;
        if (w == 0) m0 |= bit; else if (w == 1) m1 |= bit;
        else if (w == 2) m2 |= bit; else m3 |= bit;
      }
      uint2* mw2 = (uint2*)(MSUW + (size_t)u * 10);
      mw2[0] = make_uint2((unsigned)ms, (unsigned)(ms >> 32));
      mw2[1] = make_uint2((unsigned)m0, (unsigned)(m0 >> 32));
      mw2[2] = make_uint2((unsigned)m1, (unsigned)(m1 >> 32));
      mw2[3] = make_uint2((unsigned)m2, (unsigned)(m2 >> 32));
      mw2[4] = make_uint2((unsigned)m3, (unsigned)(m3 >> 32));
      W3T_s[x * HD + t] = f2b(sW3[t * SSLOT + x]);
    } else {
      const int n = x - 64;
      W2T_o[n * HD + t] = f2b(oW2[t * HD + n]);
      W2T_s[n * HD + t] = f2b(sW2[t * HD + n]);
      if (n < SSLOT) {
        W2T_o[(n + 192) * HD + t] = f2b(oW2[t * HD + n + 192]);
        W2T_s[(n + 192) * HD + t] = f2b(sW2[t * HD + n + 192]);
      }
    }
    return;
  }
  // ---- layer-1, direct transposed write ----
  const int b0 = (blockIdx.y - 1) * 8;
  const int sg = x >> 6, ng = x & 63;
  const int s = t & 63, ni = t >> 6;
  const int n = ng * 4 + ni;
  const int rbase = (sg == 0) ? s * 16 : 1024 + ((sg - 1) * 64 + s) * 16;
  float wo[16], wsv[16];
  #pragma unroll
  for (int d = 0; d < 16; ++d) {
    wo[d]  = oW1[(rbase + d) * HD + n];
    wsv[d] = sW1[(rbase + d) * HD + n];
  }
  const float* xbase = (sg == 0) ? xs : (xu + (size_t)(sg - 1) * 64 * 16);
  const int xstride = (sg == 0) ? 1024 : 4096;
  const int kk = sg * 64 + s;
  #pragma unroll
  for (int bi = 0; bi < 8; ++bi) {
    const int b = b0 + bi;
    const float4* xp = (const float4*)(xbase + (size_t)b * xstride + s * 16);
    float4 x0 = xp[0], x1 = xp[1], x2 = xp[2], x3 = xp[3];
    float ao, as;
    ao  = x0.x * wo[0];  as  = x0.x * wsv[0];
    ao = fmaf(x0.y, wo[1], ao);  as = fmaf(x0.y, wsv[1], as);
    ao = fmaf(x0.z, wo[2], ao);  as = fmaf(x0.z, wsv[2], as);
    ao = fmaf(x0.w, wo[3], ao);  as = fmaf(x0.w, wsv[3], as);
    ao = fmaf(x1.x, wo[4], ao);  as = fmaf(x1.x, wsv[4], as);
    ao = fmaf(x1.y, wo[5], ao);  as = fmaf(x1.y, wsv[5], as);
    ao = fmaf(x1.z, wo[6], ao);  as = fmaf(x1.z, wsv[6], as);
    ao = fmaf(x1.w, wo[7], ao);  as = fmaf(x1.w, wsv[7], as);
    ao = fmaf(x2.x, wo[8], ao);  as = fmaf(x2.x, wsv[8], as);
    ao = fmaf(x2.y, wo[9], ao);  as = fmaf(x2.y, wsv[9], as);
    ao = fmaf(x2.z, wo[10], ao); as = fmaf(x2.z, wsv[10], as);
    ao = fmaf(x2.w, wo[11], ao); as = fmaf(x2.w, wsv[11], as);
    ao = fmaf(x3.x, wo[12], ao); as = fmaf(x3.x, wsv[12], as);
    ao = fmaf(x3.y, wo[13], ao); as = fmaf(x3.y, wsv[13], as);
    ao = fmaf(x3.z, wo[14], ao); as = fmaf(x3.z, wsv[14], as);
    ao = fmaf(x3.w, wo[15], ao); as = fmaf(x3.w, wsv[15], as);
    const size_t off = (size_t)(b * 256 + n) * KTOT + kk;
    PQT_o[off] = f2b(ao);
    PQT_s[off] = f2b(as);
  }
}

// ---------------------------------------------------------------------------
// K2: h1 via mask-MFMA, both operands LDS-resident, k-chunked panel.
// grid (128, 2, 2): x -> (b = x>>1, user-half uh = x&1); y = mlp; z = n-half.
// 256 thr. LDS: pan [128 n][168] (43008 B) + masks 128x10 u32 (5120 B) = 48 KB
// -> 2-3 blocks/CU. Wave w: 32 users x 128 cols, acc[2][8].
// ---------------------------------------------------------------------------
__global__ __launch_bounds__(256) void k_h1(
    const unsigned* __restrict__ MSUW,
    const __hip_bfloat16* __restrict__ PQT_o, const __hip_bfloat16* __restrict__ PQT_s,
    const float* __restrict__ ob1, const float* __restrict__ sb1,
    __hip_bfloat16* __restrict__ h1o, __hip_bfloat16* __restrict__ h1s) {
  const int b = blockIdx.x >> 1, uh = blockIdx.x & 1;
  const int mlp = blockIdx.y, nh = blockIdx.z;
  const int n0 = nh * 128;
  const int t = threadIdx.x;
  const __hip_bfloat16* PQT = mlp ? PQT_s : PQT_o;
  const float* b1 = mlp ? sb1 : ob1;
  __hip_bfloat16* h1 = mlp ? h1s : h1o;

  __shared__ __align__(16) char smem[48128];
  short* pan = (short*)smem;                   // [128][168], no swizzle needed
  unsigned* mskL = (unsigned*)(smem + 43008);  // 1280 u32

  {
    const unsigned* g = MSUW + (size_t)(b * 256 + uh * 128) * 10;
    #pragma unroll
    for (int i = 0; i < 5; ++i) mskL[t + 256 * i] = g[t + 256 * i];
  }
  const int lane = t & 63, w = t >> 6;
  const int lo = lane & 15, hi = lane >> 4;
  f32x4 acc[2][8] = {};
  for (int kc = 0; kc < 2; ++kc) {
    if (kc) __syncthreads();                   // protect pan reuse
    {
      const int r = t >> 1, c4 = t & 1;
      const __hip_bfloat16* src = PQT + (size_t)(b * 256 + n0 + r) * KTOT + kc * 160;
      #pragma unroll
      for (int i = 0; i < 10; ++i) {
        int cc = c4 + 2 * i;
        *(short8*)&pan[r * 168 + cc * 8] = *(const short8*)(src + cc * 8);
      }
    }
    __syncthreads();
    #pragma unroll
    for (int kt2 = 0; kt2 < 5; ++kt2) {
      const int kt = kc * 5 + kt2;
      short8 af[2], bf[8];
      #pragma unroll
      for (int rb = 0; rb < 2; ++rb) {
        int lu = w * 32 + rb * 16 + lo;
        unsigned m = mskL[lu * 10 + kt];
        unsigned by = (m >> (hi * 8)) & 0xFFu;
        union { unsigned u[4]; short8 s; } cv;
        cv.u[0] = ((by & 1u)  ? 0x3F80u : 0u) | ((by & 2u)   ? 0x3F800000u : 0u);
        cv.u[1] = ((by & 4u)  ? 0x3F80u : 0u) | ((by & 8u)   ? 0x3F800000u : 0u);
        cv.u[2] = ((by & 16u) ? 0x3F80u : 0u) | ((by & 32u)  ? 0x3F800000u : 0u);
        cv.u[3] = ((by & 64u) ? 0x3F80u : 0u) | ((by & 128u) ? 0x3F800000u : 0u);
        af[rb] = cv.s;
      }
      #pragma unroll
      for (int cb = 0; cb < 8; ++cb) {
        int n = cb * 16 + lo;
        bf[cb] = *(const short8*)&pan[n * 168 + (kt2 * 4 + hi) * 8];
      }
      #pragma unroll
      for (int rb = 0; rb < 2; ++rb)
        #pragma unroll
        for (int cb = 0; cb < 8; ++cb)
          acc[rb][cb] = __builtin_amdgcn_mfma_f32_16x16x32_bf16(af[rb], bf[cb], acc[rb][cb], 0, 0, 0);
    }
  }
  #pragma unroll
  for (int cb = 0; cb < 8; ++cb) {
    int n = cb * 16 + lo;
    float bv = b1[n0 + n];
    #pragma unroll
    for (int rb = 0; rb < 2; ++rb) {
      #pragma unroll
      for (int j = 0; j < 4; ++j) {
        int u = b * 256 + uh * 128 + w * 32 + rb * 16 + hi * 4 + j;
        h1[(size_t)u * HD + n0 + n] = f2b(fmaxf(acc[rb][cb][j] + bv, 0.f));
      }
    }
  }
}

// ---------------------------------------------------------------------------
// K3: layer-2 GEMM + heads (round-9 validated code).
// ---------------------------------------------------------------------------
__global__ __launch_bounds__(256) void k_heads(
    const __hip_bfloat16* __restrict__ h1o, const __hip_bfloat16* __restrict__ h1s,
    const __hip_bfloat16* __restrict__ W2T_o, const __hip_bfloat16* __restrict__ W2T_s,
    const float* __restrict__ ob2, const float* __restrict__ sb2,
    const float* __restrict__ oW3, const float* __restrict__ ob3,
    const __hip_bfloat16* __restrict__ W3T_s, const float* __restrict__ sb3,
    const unsigned long long* __restrict__ connS,
    float* __restrict__ out) {
  const int mlp = blockIdx.y;
  const int x = blockIdx.x;
  const int blk = (x & 7) * 64 + (x >> 3);
  const int u0 = blk * 32;
  const int t = threadIdx.x, lane = t & 63, wid = t >> 6;
  const int lo = lane & 15, hi = lane >> 4;

  const __hip_bfloat16* A   = mlp ? h1s : h1o;
  const __hip_bfloat16* W2T = mlp ? W2T_s : W2T_o;
  const float* b2 = mlp ? sb2 : ob2;

  __shared__ __align__(16) char lds[16384 + 36864];
  short* As = (short*)lds;
  short* Bs = (short*)(lds + 16384);
  float* part = (float*)lds;

  #pragma unroll
  for (int i = 0; i < 4; ++i) {
    int c = t + i * 256;
    int row = c >> 5, cc = c & 31;
    *(short8*)&As[row * 256 + (cc ^ (row & 7)) * 8] =
        *(const short8*)(A + (size_t)(u0 + row) * HD + cc * 8);
  }
  __syncthreads();

  f32x4 acc2[2][4] = {};
  for (int ks = 0; ks < 8; ++ks) {
    if (ks) __syncthreads();
    #pragma unroll
    for (int i = 0; i < 4; ++i) {
      int c = t + i * 256;
      int n = c >> 2, kc = c & 3;
      *(short8*)&Bs[n * 72 + kc * 8] =
          *(const short8*)(W2T + (size_t)n * HD + ks * 32 + kc * 8);
    }
    __syncthreads();
    short8 af[2], bf[4];
    #pragma unroll
    for (int rb = 0; rb < 2; ++rb) {
      int row = rb * 16 + lo;
      int ca = ks * 4 + hi;
      af[rb] = *(const short8*)&As[row * 256 + (ca ^ (row & 7)) * 8];
    }
    #pragma unroll
    for (int cb = 0; cb < 4; ++cb) {
      int n = wid * 64 + cb * 16 + lo;
      bf[cb] = *(const short8*)&Bs[n * 72 + hi * 8];
    }
    #pragma unroll
    for (int rb = 0; rb < 2; ++rb)
      #pragma unroll
      for (int cb = 0; cb < 4; ++cb)
        acc2[rb][cb] = __builtin_amdgcn_mfma_f32_16x16x32_bf16(af[rb], bf[cb], acc2[rb][cb], 0, 0, 0);
  }
  __syncthreads();

  if (mlp == 0) {
    float p0[2][4] = {}, p1[2][4] = {};
    #pragma unroll
    for (int cb = 0; cb < 4; ++cb) {
      int n = wid * 64 + cb * 16 + lo;
      float bs = b2[n], w0 = oW3[2 * n], w1 = oW3[2 * n + 1];
      #pragma unroll
      for (int rb = 0; rb < 2; ++rb)
        #pragma unroll
        for (int j = 0; j < 4; ++j) {
          float sig = 1.0f / (1.0f + __expf(-(acc2[rb][cb][j] + bs)));
          p0[rb][j] = fmaf(sig, w0, p0[rb][j]);
          p1[rb][j] = fmaf(sig, w1, p1[rb][j]);
        }
    }
    #pragma unroll
    for (int rb = 0; rb < 2; ++rb)
      #pragma unroll
      for (int j = 0; j < 4; ++j) {
        #pragma unroll
        for (int off = 1; off < 16; off <<= 1) {
          p0[rb][j] += __shfl_xor(p0[rb][j], off, 64);
          p1[rb][j] += __shfl_xor(p1[rb][j], off, 64);
        }
        if (lo == 0) {
          int row = rb * 16 + hi * 4 + j;
          part[wid * 64 + row * 2 + 0] = p0[rb][j];
          part[wid * 64 + row * 2 + 1] = p1[rb][j];
        }
      }
    __syncthreads();
    if (t < 32) {
      float q0 = part[t * 2] + part[64 + t * 2] + part[128 + t * 2] + part[192 + t * 2] + ob3[0];
      float q1 = part[t * 2 + 1] + part[64 + t * 2 + 1] + part[128 + t * 2 + 1] + part[192 + t * 2 + 1] + ob3[1];
      float m2 = fmaxf(q0, q1);
      float e0 = __expf(q0 - m2), e1 = __expf(q1 - m2);
      float iv = 1.0f / (e0 + e1);
      float2 r; r.x = e0 * iv; r.y = e1 * iv;
      *(float2*)(out + (size_t)(u0 + t) * 2) = r;
    }
  } else {
    short* sel = As;
    #pragma unroll
    for (int cb = 0; cb < 4; ++cb) {
      int n = wid * 64 + cb * 16 + lo;
      float bs = b2[n];
      #pragma unroll
      for (int rb = 0; rb < 2; ++rb)
        #pragma unroll
        for (int j = 0; j < 4; ++j) {
          int row = rb * 16 + hi * 4 + j;
          float sig = 1.0f / (1.0f + __expf(-(acc2[rb][cb][j] + bs)));
          sel[row * 256 + ((n >> 3) ^ (row & 7)) * 8 + (n & 7)] = (short)pack2(sig, 0.f);
        }
    }
    __syncthreads();
    if (wid < 2) {
      f32x4 acc3[4] = {};
      #pragma unroll
      for (int ks = 0; ks < 8; ++ks) {
        int row = wid * 16 + lo;
        int ca = ks * 4 + hi;
        short8 af = *(const short8*)&sel[row * 256 + (ca ^ (row & 7)) * 8];
        #pragma unroll
        for (int cb = 0; cb < 4; ++cb) {
          short8 bf = *(const short8*)(W3T_s + (size_t)(cb * 16 + lo) * HD + ks * 32 + hi * 8);
          acc3[cb] = __builtin_amdgcn_mfma_f32_16x16x32_bf16(af, bf, acc3[cb], 0, 0, 0);
        }
      }
      float sb3n[4];
      #pragma unroll
      for (int cb = 0; cb < 4; ++cb) sb3n[cb] = sb3[cb * 16 + lo];
      const int ubase = u0 + wid * 16 + hi * 4;
      #pragma unroll
      for (int j = 0; j < 4; ++j) {
        unsigned long long m = connS[ubase + j];
        float v[4]; bool ok[4];
        float mx = -INFINITY;
        #pragma unroll
        for (int cb = 0; cb < 4; ++cb) {
          int n = cb * 16 + lo;
          ok[cb] = (m >> n) & 1ull;
          v[cb] = ok[cb] ? (acc3[cb][j] + sb3n[cb]) : -INFINITY;
          mx = fmaxf(mx, v[cb]);
        }
        #pragma unroll
        for (int off = 1; off < 16; off <<= 1) mx = fmaxf(mx, __shfl_xor(mx, off, 64));
        float e[4], ssum = 0.f;
        #pragma unroll
        for (int cb = 0; cb < 4; ++cb) {
          e[cb] = ok[cb] ? __expf(v[cb] - mx) : 0.f;
          ssum += e[cb];
        }
        #pragma unroll
        for (int off = 1; off < 16; off <<= 1) ssum += __shfl_xor(ssum, off, 64);
        float iv = 1.0f / ssum;
        #pragma unroll
        for (int cb = 0; cb < 4; ++cb) {
          int n = cb * 16 + lo;
          out[(size_t)NUSER * 2 + (size_t)(ubase + j) * SSLOT + n] = e[cb] * iv;
        }
      }
    }
  }
}

// ---------------------------------------------------------------------------
extern "C" void kernel_launch(void* const* d_in, const int* in_sizes, int n_in,
                              void* d_out, int out_size, void* d_ws, size_t ws_size,
                              hipStream_t stream) {
  const float* x_user   = (const float*)d_in[0];
  const float* x_server = (const float*)d_in[1];
  const int*   dst_u2s  = (const int*)d_in[3];
  const int*   dst_u2u  = (const int*)d_in[5];
  const float* oW1 = (const float*)d_in[6];
  const float* ob1 = (const float*)d_in[7];
  const float* oW2 = (const float*)d_in[8];
  const float* ob2 = (const float*)d_in[9];
  const float* oW3 = (const float*)d_in[10];
  const float* ob3 = (const float*)d_in[11];
  const float* sW1 = (const float*)d_in[12];
  const float* sb1 = (const float*)d_in[13];
  const float* sW2 = (const float*)d_in[14];
  const float* sb2 = (const float*)d_in[15];
  const float* sW3 = (const float*)d_in[16];
  const float* sb3 = (const float*)d_in[17];

  char* ws = (char*)d_ws;
  unsigned long long* connS = (unsigned long long*)(ws + 0);         // 128 KB
  unsigned*       MSUW  = (unsigned*)(ws + 131072);                  // 640 KB
  __hip_bfloat16* PQT_o = (__hip_bfloat16*)(ws + 786432);            // 10 MB
  __hip_bfloat16* PQT_s = (__hip_bfloat16*)(ws + 11272192);          // 10 MB
  __hip_bfloat16* h1o   = (__hip_bfloat16*)(ws + 21757952);          // 8 MB
  __hip_bfloat16* h1s   = (__hip_bfloat16*)(ws + 30146560);          // 8 MB
  __hip_bfloat16* W2T_o = (__hip_bfloat16*)(ws + 38535168);          // 128 KB
  __hip_bfloat16* W2T_s = (__hip_bfloat16*)(ws + 38666240);          // 128 KB
  __hip_bfloat16* W3T_s = (__hip_bfloat16*)(ws + 38797312);          // 32 KB
  float* out = (float*)d_out;

  k_p1<<<dim3(320, 9), 256, 0, stream>>>(
      dst_u2s, dst_u2u, oW2, sW2, sW3, x_user, x_server, oW1, sW1,
      connS, MSUW, W2T_o, W2T_s, W3T_s, PQT_o, PQT_s);
  k_h1<<<dim3(128, 2, 2), 256, 0, stream>>>(MSUW, PQT_o, PQT_s, ob1, sb1, h1o, h1s);
  k_heads<<<dim3(512, 2), 256, 0, stream>>>(h1o, h1s, W2T_o, W2T_s, ob2, sb2,
                                            oW3, ob3, W3T_s, sb3, connS, out);
}

// Round 13
// 60.285 us; speedup vs baseline: 4.1497x; 2.6801x over previous
//
#include <hip/hip_runtime.h>
#include <hip/hip_bf16.h>
#include <math.h>
#include <cstdint>

#define NUSER 16384   // B*U
#define BB    64
#define UU    256
#define SSLOT 64
#define HD    256
#define KTOT  320
#define DEGS  8
#define DEGU  16

typedef __attribute__((ext_vector_type(8))) short short8;
typedef __attribute__((ext_vector_type(4))) float f32x4;

static __device__ __forceinline__ __hip_bfloat16 f2b(float x) { return __float2bfloat16(x); }
static __device__ __forceinline__ unsigned pack2(float x, float y) {
  union { __hip_bfloat16 h[2]; unsigned u; } cv;
  cv.h[0] = f2b(x); cv.h[1] = f2b(y);
  return cv.u;
}

// ---------------------------------------------------------------------------
// K1 (round-9 verbatim): merged prep + per-slot layer-1 products.
// y==0, x<64: connS + mask words.  y==0, x>=64: weight transposes.
// y>=1: pq body (coalesced weight loads lane->column), 8 batches per block.
// ---------------------------------------------------------------------------
__global__ __launch_bounds__(256) void k_prep_pq(
    const int* __restrict__ dst_u2s, const int* __restrict__ dst_u2u,
    const float* __restrict__ oW2, const float* __restrict__ sW2,
    const float* __restrict__ sW3,
    const float* __restrict__ xu, const float* __restrict__ xs,
    const float* __restrict__ oW1, const float* __restrict__ sW1,
    unsigned long long* __restrict__ connS, unsigned* __restrict__ MSUW,
    __hip_bfloat16* __restrict__ W2T_o, __hip_bfloat16* __restrict__ W2T_s,
    __hip_bfloat16* __restrict__ W3T_s,
    __hip_bfloat16* __restrict__ P_o, __hip_bfloat16* __restrict__ P_s,
    __hip_bfloat16* __restrict__ Q_o, __hip_bfloat16* __restrict__ Q_s) {
  const int t = threadIdx.x;
  if (blockIdx.y == 0) {
    const int blk = blockIdx.x;
    if (blk < 64) {
      const int u = blk * 256 + t;
      unsigned long long ms = 0ull;
      #pragma unroll
      for (int i = 0; i < DEGS; ++i) ms |= 1ull << (dst_u2s[u * DEGS + i] & 63);
      connS[u] = ms;
      unsigned long long m0 = 0, m1 = 0, m2 = 0, m3 = 0;
      #pragma unroll
      for (int i = 0; i < DEGU; ++i) {
        int slot = dst_u2u[u * DEGU + i] & 255;
        unsigned long long bit = 1ull << (slot & 63);
        int w = slot >> 6;
        if (w == 0) m0 |= bit; else if (w == 1) m1 |= bit;
        else if (w == 2) m2 |= bit; else m3 |= bit;
      }
      unsigned* mw = MSUW + (size_t)u * 10;
      uint2* mw2 = (uint2*)mw;
      mw2[0] = make_uint2((unsigned)ms, (unsigned)(ms >> 32));
      mw2[1] = make_uint2((unsigned)m0, (unsigned)(m0 >> 32));
      mw2[2] = make_uint2((unsigned)m1, (unsigned)(m1 >> 32));
      mw2[3] = make_uint2((unsigned)m2, (unsigned)(m2 >> 32));
      mw2[4] = make_uint2((unsigned)m3, (unsigned)(m3 >> 32));
    } else {
      const int n = blk - 64;
      W2T_o[n * HD + t] = f2b(oW2[t * HD + n]);
      W2T_s[n * HD + t] = f2b(sW2[t * HD + n]);
      if (n < SSLOT) W3T_s[n * HD + t] = f2b(sW3[t * SSLOT + n]);
    }
    return;
  }
  // ---- pq body ----
  const int wg = blockIdx.x;            // 0..63 server slots, 64..319 user slots
  const int b0 = (blockIdx.y - 1) * 8;
  __shared__ float lx[8 * 16];
  const bool isS = wg < SSLOT;
  const int slot = isS ? wg : wg - SSLOT;
  if (t < 8 * 16) {
    int b = b0 + (t >> 4), d = t & 15;
    lx[t] = isS ? xs[(b * SSLOT + slot) * 16 + d] : xu[(b * UU + slot) * 16 + d];
  }
  __syncthreads();
  float wo[16], wsv[16];
  const int rbase = isS ? slot * 16 : SSLOT * 16 + slot * 16;
  #pragma unroll
  for (int d = 0; d < 16; ++d) {
    wo[d] = oW1[(rbase + d) * HD + t];
    wsv[d] = sW1[(rbase + d) * HD + t];
  }
  __hip_bfloat16* Ro = isS ? P_o : Q_o;
  __hip_bfloat16* Rs = isS ? P_s : Q_s;
  const int rows = isS ? SSLOT : UU;
  #pragma unroll
  for (int bi = 0; bi < 8; ++bi) {
    float ao = 0.f, as = 0.f;
    #pragma unroll
    for (int q = 0; q < 4; ++q) {
      float4 x4 = *(const float4*)&lx[bi * 16 + q * 4];
      ao = fmaf(x4.x, wo[q*4+0], ao); as = fmaf(x4.x, wsv[q*4+0], as);
      ao = fmaf(x4.y, wo[q*4+1], ao); as = fmaf(x4.y, wsv[q*4+1], as);
      ao = fmaf(x4.z, wo[q*4+2], ao); as = fmaf(x4.z, wsv[q*4+2], as);
      ao = fmaf(x4.w, wo[q*4+3], ao); as = fmaf(x4.w, wsv[q*4+3], as);
    }
    Ro[((b0 + bi) * rows + slot) * HD + t] = f2b(ao);
    Rs[((b0 + bi) * rows + slot) * HD + t] = f2b(as);
  }
}

// ---------------------------------------------------------------------------
// K2 (round-9 verbatim): transpose P,Q -> PQT[b][n][320] via LDS.
// ---------------------------------------------------------------------------
__global__ __launch_bounds__(256) void k_tr(
    const __hip_bfloat16* __restrict__ P_o, const __hip_bfloat16* __restrict__ P_s,
    const __hip_bfloat16* __restrict__ Q_o, const __hip_bfloat16* __restrict__ Q_s,
    __hip_bfloat16* __restrict__ PQT_o, __hip_bfloat16* __restrict__ PQT_s) {
  const int b = blockIdx.x, mlp = blockIdx.y, nc = blockIdx.z;
  const int n0 = nc * 64;
  const int t = threadIdx.x;
  const __hip_bfloat16* P = mlp ? P_s : P_o;
  const __hip_bfloat16* Q = mlp ? Q_s : Q_o;
  __hip_bfloat16* PQT = mlp ? PQT_s : PQT_o;
  __shared__ __align__(16) short lds[64 * 72];
  for (int kt = 0; kt < 5; ++kt) {
    const __hip_bfloat16* src = (kt == 0) ? (P + (size_t)(b * SSLOT) * HD)
                                          : (Q + (size_t)(b * UU + (kt - 1) * 64) * HD);
    const int kout = (kt == 0) ? 0 : 64 + (kt - 1) * 64;
    #pragma unroll
    for (int i = 0; i < 2; ++i) {
      int c = t + i * 256;
      int row = c >> 3, cc = c & 7;
      *(short8*)&lds[row * 72 + cc * 8] =
          *(const short8*)(src + (size_t)row * HD + n0 + cc * 8);
    }
    __syncthreads();
    #pragma unroll
    for (int i = 0; i < 2; ++i) {
      int c = t + i * 256;
      int nrow = c >> 3, kc = c & 7;
      short8 v;
      #pragma unroll
      for (int e = 0; e < 8; ++e) v[e] = lds[(kc * 8 + e) * 72 + nrow];
      *(short8*)(PQT + (size_t)(b * 256 + n0 + nrow) * KTOT + kout + kc * 8) = v;
    }
    __syncthreads();
  }
}

// ---------------------------------------------------------------------------
// K3 (round-12 version, validated): h1 via mask-MFMA, k-chunked 48 KB LDS.
// grid (128,2,2), 256 thr, 2-3 blocks/CU.
// ---------------------------------------------------------------------------
__global__ __launch_bounds__(256) void k_h1(
    const unsigned* __restrict__ MSUW,
    const __hip_bfloat16* __restrict__ PQT_o, const __hip_bfloat16* __restrict__ PQT_s,
    const float* __restrict__ ob1, const float* __restrict__ sb1,
    __hip_bfloat16* __restrict__ h1o, __hip_bfloat16* __restrict__ h1s) {
  const int b = blockIdx.x >> 1, uh = blockIdx.x & 1;
  const int mlp = blockIdx.y, nh = blockIdx.z;
  const int n0 = nh * 128;
  const int t = threadIdx.x;
  const __hip_bfloat16* PQT = mlp ? PQT_s : PQT_o;
  const float* b1 = mlp ? sb1 : ob1;
  __hip_bfloat16* h1 = mlp ? h1s : h1o;

  __shared__ __align__(16) char smem[48128];
  short* pan = (short*)smem;                   // [128][168], 2-way-free stride
  unsigned* mskL = (unsigned*)(smem + 43008);  // 1280 u32

  {
    const unsigned* g = MSUW + (size_t)(b * 256 + uh * 128) * 10;
    #pragma unroll
    for (int i = 0; i < 5; ++i) mskL[t + 256 * i] = g[t + 256 * i];
  }
  const int lane = t & 63, w = t >> 6;
  const int lo = lane & 15, hi = lane >> 4;
  f32x4 acc[2][8] = {};
  for (int kc = 0; kc < 2; ++kc) {
    if (kc) __syncthreads();                   // protect pan reuse
    {
      const int r = t >> 1, c4 = t & 1;
      const __hip_bfloat16* src = PQT + (size_t)(b * 256 + n0 + r) * KTOT + kc * 160;
      #pragma unroll
      for (int i = 0; i < 10; ++i) {
        int cc = c4 + 2 * i;
        *(short8*)&pan[r * 168 + cc * 8] = *(const short8*)(src + cc * 8);
      }
    }
    __syncthreads();
    #pragma unroll
    for (int kt2 = 0; kt2 < 5; ++kt2) {
      const int kt = kc * 5 + kt2;
      short8 af[2], bf[8];
      #pragma unroll
      for (int rb = 0; rb < 2; ++rb) {
        int lu = w * 32 + rb * 16 + lo;
        unsigned m = mskL[lu * 10 + kt];
        unsigned by = (m >> (hi * 8)) & 0xFFu;
        union { unsigned u[4]; short8 s; } cv;
        cv.u[0] = ((by & 1u)  ? 0x3F80u : 0u) | ((by & 2u)   ? 0x3F800000u : 0u);
        cv.u[1] = ((by & 4u)  ? 0x3F80u : 0u) | ((by & 8u)   ? 0x3F800000u : 0u);
        cv.u[2] = ((by & 16u) ? 0x3F80u : 0u) | ((by & 32u)  ? 0x3F800000u : 0u);
        cv.u[3] = ((by & 64u) ? 0x3F80u : 0u) | ((by & 128u) ? 0x3F800000u : 0u);
        af[rb] = cv.s;
      }
      #pragma unroll
      for (int cb = 0; cb < 8; ++cb) {
        int n = cb * 16 + lo;
        bf[cb] = *(const short8*)&pan[n * 168 + (kt2 * 4 + hi) * 8];
      }
      #pragma unroll
      for (int rb = 0; rb < 2; ++rb)
        #pragma unroll
        for (int cb = 0; cb < 8; ++cb)
          acc[rb][cb] = __builtin_amdgcn_mfma_f32_16x16x32_bf16(af[rb], bf[cb], acc[rb][cb], 0, 0, 0);
    }
  }
  #pragma unroll
  for (int cb = 0; cb < 8; ++cb) {
    int n = cb * 16 + lo;
    float bv = b1[n0 + n];
    #pragma unroll
    for (int rb = 0; rb < 2; ++rb) {
      #pragma unroll
      for (int j = 0; j < 4; ++j) {
        int u = b * 256 + uh * 128 + w * 32 + rb * 16 + hi * 4 + j;
        h1[(size_t)u * HD + n0 + n] = f2b(fmaxf(acc[rb][cb][j] + bv, 0.f));
      }
    }
  }
}

// ---------------------------------------------------------------------------
// K4 (round-9 verbatim): layer-2 GEMM + heads.
// ---------------------------------------------------------------------------
__global__ __launch_bounds__(256) void k_heads(
    const __hip_bfloat16* __restrict__ h1o, const __hip_bfloat16* __restrict__ h1s,
    const __hip_bfloat16* __restrict__ W2T_o, const __hip_bfloat16* __restrict__ W2T_s,
    const float* __restrict__ ob2, const float* __restrict__ sb2,
    const float* __restrict__ oW3, const float* __restrict__ ob3,
    const __hip_bfloat16* __restrict__ W3T_s, const float* __restrict__ sb3,
    const unsigned long long* __restrict__ connS,
    float* __restrict__ out) {
  const int mlp = blockIdx.y;
  const int x = blockIdx.x;
  const int blk = (x & 7) * 64 + (x >> 3);
  const int u0 = blk * 32;
  const int t = threadIdx.x, lane = t & 63, wid = t >> 6;
  const int lo = lane & 15, hi = lane >> 4;

  const __hip_bfloat16* A   = mlp ? h1s : h1o;
  const __hip_bfloat16* W2T = mlp ? W2T_s : W2T_o;
  const float* b2 = mlp ? sb2 : ob2;

  __shared__ __align__(16) char lds[16384 + 36864];
  short* As = (short*)lds;
  short* Bs = (short*)(lds + 16384);
  float* part = (float*)lds;

  #pragma unroll
  for (int i = 0; i < 4; ++i) {
    int c = t + i * 256;
    int row = c >> 5, cc = c & 31;
    *(short8*)&As[row * 256 + (cc ^ (row & 7)) * 8] =
        *(const short8*)(A + (size_t)(u0 + row) * HD + cc * 8);
  }
  __syncthreads();

  f32x4 acc2[2][4] = {};
  for (int ks = 0; ks < 8; ++ks) {
    if (ks) __syncthreads();
    #pragma unroll
    for (int i = 0; i < 4; ++i) {
      int c = t + i * 256;
      int n = c >> 2, kc = c & 3;
      *(short8*)&Bs[n * 72 + kc * 8] =
          *(const short8*)(W2T + (size_t)n * HD + ks * 32 + kc * 8);
    }
    __syncthreads();
    short8 af[2], bf[4];
    #pragma unroll
    for (int rb = 0; rb < 2; ++rb) {
      int row = rb * 16 + lo;
      int ca = ks * 4 + hi;
      af[rb] = *(const short8*)&As[row * 256 + (ca ^ (row & 7)) * 8];
    }
    #pragma unroll
    for (int cb = 0; cb < 4; ++cb) {
      int n = wid * 64 + cb * 16 + lo;
      bf[cb] = *(const short8*)&Bs[n * 72 + hi * 8];
    }
    #pragma unroll
    for (int rb = 0; rb < 2; ++rb)
      #pragma unroll
      for (int cb = 0; cb < 4; ++cb)
        acc2[rb][cb] = __builtin_amdgcn_mfma_f32_16x16x32_bf16(af[rb], bf[cb], acc2[rb][cb], 0, 0, 0);
  }
  __syncthreads();

  if (mlp == 0) {
    float p0[2][4] = {}, p1[2][4] = {};
    #pragma unroll
    for (int cb = 0; cb < 4; ++cb) {
      int n = wid * 64 + cb * 16 + lo;
      float bs = b2[n], w0 = oW3[2 * n], w1 = oW3[2 * n + 1];
      #pragma unroll
      for (int rb = 0; rb < 2; ++rb)
        #pragma unroll
        for (int j = 0; j < 4; ++j) {
          float sig = 1.0f / (1.0f + __expf(-(acc2[rb][cb][j] + bs)));
          p0[rb][j] = fmaf(sig, w0, p0[rb][j]);
          p1[rb][j] = fmaf(sig, w1, p1[rb][j]);
        }
    }
    #pragma unroll
    for (int rb = 0; rb < 2; ++rb)
      #pragma unroll
      for (int j = 0; j < 4; ++j) {
        #pragma unroll
        for (int off = 1; off < 16; off <<= 1) {
          p0[rb][j] += __shfl_xor(p0[rb][j], off, 64);
          p1[rb][j] += __shfl_xor(p1[rb][j], off, 64);
        }
        if (lo == 0) {
          int row = rb * 16 + hi * 4 + j;
          part[wid * 64 + row * 2 + 0] = p0[rb][j];
          part[wid * 64 + row * 2 + 1] = p1[rb][j];
        }
      }
    __syncthreads();
    if (t < 32) {
      float q0 = part[t * 2] + part[64 + t * 2] + part[128 + t * 2] + part[192 + t * 2] + ob3[0];
      float q1 = part[t * 2 + 1] + part[64 + t * 2 + 1] + part[128 + t * 2 + 1] + part[192 + t * 2 + 1] + ob3[1];
      float m2 = fmaxf(q0, q1);
      float e0 = __expf(q0 - m2), e1 = __expf(q1 - m2);
      float iv = 1.0f / (e0 + e1);
      float2 r; r.x = e0 * iv; r.y = e1 * iv;
      *(float2*)(out + (size_t)(u0 + t) * 2) = r;
    }
  } else {
    short* sel = As;
    #pragma unroll
    for (int cb = 0; cb < 4; ++cb) {
      int n = wid * 64 + cb * 16 + lo;
      float bs = b2[n];
      #pragma unroll
      for (int rb = 0; rb < 2; ++rb)
        #pragma unroll
        for (int j = 0; j < 4; ++j) {
          int row = rb * 16 + hi * 4 + j;
          float sig = 1.0f / (1.0f + __expf(-(acc2[rb][cb][j] + bs)));
          sel[row * 256 + ((n >> 3) ^ (row & 7)) * 8 + (n & 7)] = (short)pack2(sig, 0.f);
        }
    }
    __syncthreads();
    if (wid < 2) {
      f32x4 acc3[4] = {};
      #pragma unroll
      for (int ks = 0; ks < 8; ++ks) {
        int row = wid * 16 + lo;
        int ca = ks * 4 + hi;
        short8 af = *(const short8*)&sel[row * 256 + (ca ^ (row & 7)) * 8];
        #pragma unroll
        for (int cb = 0; cb < 4; ++cb) {
          short8 bf = *(const short8*)(W3T_s + (size_t)(cb * 16 + lo) * HD + ks * 32 + hi * 8);
          acc3[cb] = __builtin_amdgcn_mfma_f32_16x16x32_bf16(af, bf, acc3[cb], 0, 0, 0);
        }
      }
      float sb3n[4];
      #pragma unroll
      for (int cb = 0; cb < 4; ++cb) sb3n[cb] = sb3[cb * 16 + lo];
      const int ubase = u0 + wid * 16 + hi * 4;
      #pragma unroll
      for (int j = 0; j < 4; ++j) {
        unsigned long long m = connS[ubase + j];
        float v[4]; bool ok[4];
        float mx = -INFINITY;
        #pragma unroll
        for (int cb = 0; cb < 4; ++cb) {
          int n = cb * 16 + lo;
          ok[cb] = (m >> n) & 1ull;
          v[cb] = ok[cb] ? (acc3[cb][j] + sb3n[cb]) : -INFINITY;
          mx = fmaxf(mx, v[cb]);
        }
        #pragma unroll
        for (int off = 1; off < 16; off <<= 1) mx = fmaxf(mx, __shfl_xor(mx, off, 64));
        float e[4], ssum = 0.f;
        #pragma unroll
        for (int cb = 0; cb < 4; ++cb) {
          e[cb] = ok[cb] ? __expf(v[cb] - mx) : 0.f;
          ssum += e[cb];
        }
        #pragma unroll
        for (int off = 1; off < 16; off <<= 1) ssum += __shfl_xor(ssum, off, 64);
        float iv = 1.0f / ssum;
        #pragma unroll
        for (int cb = 0; cb < 4; ++cb) {
          int n = cb * 16 + lo;
          out[(size_t)NUSER * 2 + (size_t)(ubase + j) * SSLOT + n] = e[cb] * iv;
        }
      }
    }
  }
}

// ---------------------------------------------------------------------------
extern "C" void kernel_launch(void* const* d_in, const int* in_sizes, int n_in,
                              void* d_out, int out_size, void* d_ws, size_t ws_size,
                              hipStream_t stream) {
  const float* x_user   = (const float*)d_in[0];
  const float* x_server = (const float*)d_in[1];
  const int*   dst_u2s  = (const int*)d_in[3];
  const int*   dst_u2u  = (const int*)d_in[5];
  const float* oW1 = (const float*)d_in[6];
  const float* ob1 = (const float*)d_in[7];
  const float* oW2 = (const float*)d_in[8];
  const float* ob2 = (const float*)d_in[9];
  const float* oW3 = (const float*)d_in[10];
  const float* ob3 = (const float*)d_in[11];
  const float* sW1 = (const float*)d_in[12];
  const float* sb1 = (const float*)d_in[13];
  const float* sW2 = (const float*)d_in[14];
  const float* sb2 = (const float*)d_in[15];
  const float* sW3 = (const float*)d_in[16];
  const float* sb3 = (const float*)d_in[17];

  char* ws = (char*)d_ws;
  unsigned long long* connS = (unsigned long long*)(ws + 0);         // 128 KB
  unsigned*       MSUW  = (unsigned*)(ws + 131072);                  // 640 KB
  __hip_bfloat16* P_o  = (__hip_bfloat16*)(ws + 786432);             // 2 MB
  __hip_bfloat16* P_s  = (__hip_bfloat16*)(ws + 2883584);            // 2 MB
  __hip_bfloat16* Q_o  = (__hip_bfloat16*)(ws + 4980736);            // 8 MB
  __hip_bfloat16* Q_s  = (__hip_bfloat16*)(ws + 13369344);           // 8 MB
  __hip_bfloat16* PQT_o = (__hip_bfloat16*)(ws + 21757952);          // 10 MB
  __hip_bfloat16* PQT_s = (__hip_bfloat16*)(ws + 32243712);          // 10 MB
  __hip_bfloat16* h1o  = (__hip_bfloat16*)(ws + 42729472);           // 8 MB
  __hip_bfloat16* h1s  = (__hip_bfloat16*)(ws + 51118080);           // 8 MB
  __hip_bfloat16* W2T_o = (__hip_bfloat16*)(ws + 59506688);          // 128 KB
  __hip_bfloat16* W2T_s = (__hip_bfloat16*)(ws + 59637760);          // 128 KB
  __hip_bfloat16* W3T_s = (__hip_bfloat16*)(ws + 59768832);          // 32 KB
  float* out = (float*)d_out;

  k_prep_pq<<<dim3(320, 9), 256, 0, stream>>>(
      dst_u2s, dst_u2u, oW2, sW2, sW3, x_user, x_server, oW1, sW1,
      connS, MSUW, W2T_o, W2T_s, W3T_s, P_o, P_s, Q_o, Q_s);
  k_tr<<<dim3(64, 2, 4), 256, 0, stream>>>(P_o, P_s, Q_o, Q_s, PQT_o, PQT_s);
  k_h1<<<dim3(128, 2, 2), 256, 0, stream>>>(MSUW, PQT_o, PQT_s, ob1, sb1, h1o, h1s);
  k_heads<<<dim3(512, 2), 256, 0, stream>>>(h1o, h1s, W2T_o, W2T_s, ob2, sb2,
                                            oW3, ob3, W3T_s, sb3, connS, out);
}

// Round 14
// 58.016 us; speedup vs baseline: 4.3120x; 1.0391x over previous
//
#include <hip/hip_runtime.h>
#include <hip/hip_bf16.h>
#include <math.h>
#include <cstdint>

#define NUSER 16384   // B*U
#define BB    64
#define UU    256
#define SSLOT 64
#define HD    256
#define KTOT  320
#define DEGS  8
#define DEGU  16

typedef __attribute__((ext_vector_type(8))) short short8;
typedef __attribute__((ext_vector_type(4))) float f32x4;

static __device__ __forceinline__ __hip_bfloat16 f2b(float x) { return __float2bfloat16(x); }
static __device__ __forceinline__ unsigned pack2(float x, float y) {
  union { __hip_bfloat16 h[2]; unsigned u; } cv;
  cv.h[0] = f2b(x); cv.h[1] = f2b(y);
  return cv.u;
}

// ---------------------------------------------------------------------------
// K1 (round-9 verbatim): merged prep + per-slot layer-1 products.
// ---------------------------------------------------------------------------
__global__ __launch_bounds__(256) void k_prep_pq(
    const int* __restrict__ dst_u2s, const int* __restrict__ dst_u2u,
    const float* __restrict__ oW2, const float* __restrict__ sW2,
    const float* __restrict__ sW3,
    const float* __restrict__ xu, const float* __restrict__ xs,
    const float* __restrict__ oW1, const float* __restrict__ sW1,
    unsigned long long* __restrict__ connS, unsigned* __restrict__ MSUW,
    __hip_bfloat16* __restrict__ W2T_o, __hip_bfloat16* __restrict__ W2T_s,
    __hip_bfloat16* __restrict__ W3T_s,
    __hip_bfloat16* __restrict__ P_o, __hip_bfloat16* __restrict__ P_s,
    __hip_bfloat16* __restrict__ Q_o, __hip_bfloat16* __restrict__ Q_s) {
  const int t = threadIdx.x;
  if (blockIdx.y == 0) {
    const int blk = blockIdx.x;
    if (blk < 64) {
      const int u = blk * 256 + t;
      unsigned long long ms = 0ull;
      #pragma unroll
      for (int i = 0; i < DEGS; ++i) ms |= 1ull << (dst_u2s[u * DEGS + i] & 63);
      connS[u] = ms;
      unsigned long long m0 = 0, m1 = 0, m2 = 0, m3 = 0;
      #pragma unroll
      for (int i = 0; i < DEGU; ++i) {
        int slot = dst_u2u[u * DEGU + i] & 255;
        unsigned long long bit = 1ull << (slot & 63);
        int w = slot >> 6;
        if (w == 0) m0 |= bit; else if (w == 1) m1 |= bit;
        else if (w == 2) m2 |= bit; else m3 |= bit;
      }
      unsigned* mw = MSUW + (size_t)u * 10;
      uint2* mw2 = (uint2*)mw;
      mw2[0] = make_uint2((unsigned)ms, (unsigned)(ms >> 32));
      mw2[1] = make_uint2((unsigned)m0, (unsigned)(m0 >> 32));
      mw2[2] = make_uint2((unsigned)m1, (unsigned)(m1 >> 32));
      mw2[3] = make_uint2((unsigned)m2, (unsigned)(m2 >> 32));
      mw2[4] = make_uint2((unsigned)m3, (unsigned)(m3 >> 32));
    } else {
      const int n = blk - 64;
      W2T_o[n * HD + t] = f2b(oW2[t * HD + n]);
      W2T_s[n * HD + t] = f2b(sW2[t * HD + n]);
      if (n < SSLOT) W3T_s[n * HD + t] = f2b(sW3[t * SSLOT + n]);
    }
    return;
  }
  // ---- pq body ----
  const int wg = blockIdx.x;
  const int b0 = (blockIdx.y - 1) * 8;
  __shared__ float lx[8 * 16];
  const bool isS = wg < SSLOT;
  const int slot = isS ? wg : wg - SSLOT;
  if (t < 8 * 16) {
    int b = b0 + (t >> 4), d = t & 15;
    lx[t] = isS ? xs[(b * SSLOT + slot) * 16 + d] : xu[(b * UU + slot) * 16 + d];
  }
  __syncthreads();
  float wo[16], wsv[16];
  const int rbase = isS ? slot * 16 : SSLOT * 16 + slot * 16;
  #pragma unroll
  for (int d = 0; d < 16; ++d) {
    wo[d] = oW1[(rbase + d) * HD + t];
    wsv[d] = sW1[(rbase + d) * HD + t];
  }
  __hip_bfloat16* Ro = isS ? P_o : Q_o;
  __hip_bfloat16* Rs = isS ? P_s : Q_s;
  const int rows = isS ? SSLOT : UU;
  #pragma unroll
  for (int bi = 0; bi < 8; ++bi) {
    float ao = 0.f, as = 0.f;
    #pragma unroll
    for (int q = 0; q < 4; ++q) {
      float4 x4 = *(const float4*)&lx[bi * 16 + q * 4];
      ao = fmaf(x4.x, wo[q*4+0], ao); as = fmaf(x4.x, wsv[q*4+0], as);
      ao = fmaf(x4.y, wo[q*4+1], ao); as = fmaf(x4.y, wsv[q*4+1], as);
      ao = fmaf(x4.z, wo[q*4+2], ao); as = fmaf(x4.z, wsv[q*4+2], as);
      ao = fmaf(x4.w, wo[q*4+3], ao); as = fmaf(x4.w, wsv[q*4+3], as);
    }
    Ro[((b0 + bi) * rows + slot) * HD + t] = f2b(ao);
    Rs[((b0 + bi) * rows + slot) * HD + t] = f2b(as);
  }
}

// ---------------------------------------------------------------------------
// K2 (round-9 verbatim): transpose P,Q -> PQT[b][n][320] via LDS.
// ---------------------------------------------------------------------------
__global__ __launch_bounds__(256) void k_tr(
    const __hip_bfloat16* __restrict__ P_o, const __hip_bfloat16* __restrict__ P_s,
    const __hip_bfloat16* __restrict__ Q_o, const __hip_bfloat16* __restrict__ Q_s,
    __hip_bfloat16* __restrict__ PQT_o, __hip_bfloat16* __restrict__ PQT_s) {
  const int b = blockIdx.x, mlp = blockIdx.y, nc = blockIdx.z;
  const int n0 = nc * 64;
  const int t = threadIdx.x;
  const __hip_bfloat16* P = mlp ? P_s : P_o;
  const __hip_bfloat16* Q = mlp ? Q_s : Q_o;
  __hip_bfloat16* PQT = mlp ? PQT_s : PQT_o;
  __shared__ __align__(16) short lds[64 * 72];
  for (int kt = 0; kt < 5; ++kt) {
    const __hip_bfloat16* src = (kt == 0) ? (P + (size_t)(b * SSLOT) * HD)
                                          : (Q + (size_t)(b * UU + (kt - 1) * 64) * HD);
    const int kout = (kt == 0) ? 0 : 64 + (kt - 1) * 64;
    #pragma unroll
    for (int i = 0; i < 2; ++i) {
      int c = t + i * 256;
      int row = c >> 3, cc = c & 7;
      *(short8*)&lds[row * 72 + cc * 8] =
          *(const short8*)(src + (size_t)row * HD + n0 + cc * 8);
    }
    __syncthreads();
    #pragma unroll
    for (int i = 0; i < 2; ++i) {
      int c = t + i * 256;
      int nrow = c >> 3, kc = c & 7;
      short8 v;
      #pragma unroll
      for (int e = 0; e < 8; ++e) v[e] = lds[(kc * 8 + e) * 72 + nrow];
      *(short8*)(PQT + (size_t)(b * 256 + n0 + nrow) * KTOT + kout + kc * 8) = v;
    }
    __syncthreads();
  }
}

// ---------------------------------------------------------------------------
// K3 (round-13 verbatim): h1 via mask-MFMA, k-chunked 48 KB LDS.
// ---------------------------------------------------------------------------
__global__ __launch_bounds__(256) void k_h1(
    const unsigned* __restrict__ MSUW,
    const __hip_bfloat16* __restrict__ PQT_o, const __hip_bfloat16* __restrict__ PQT_s,
    const float* __restrict__ ob1, const float* __restrict__ sb1,
    __hip_bfloat16* __restrict__ h1o, __hip_bfloat16* __restrict__ h1s) {
  const int b = blockIdx.x >> 1, uh = blockIdx.x & 1;
  const int mlp = blockIdx.y, nh = blockIdx.z;
  const int n0 = nh * 128;
  const int t = threadIdx.x;
  const __hip_bfloat16* PQT = mlp ? PQT_s : PQT_o;
  const float* b1 = mlp ? sb1 : ob1;
  __hip_bfloat16* h1 = mlp ? h1s : h1o;

  __shared__ __align__(16) char smem[48128];
  short* pan = (short*)smem;                   // [128][168]
  unsigned* mskL = (unsigned*)(smem + 43008);  // 1280 u32

  {
    const unsigned* g = MSUW + (size_t)(b * 256 + uh * 128) * 10;
    #pragma unroll
    for (int i = 0; i < 5; ++i) mskL[t + 256 * i] = g[t + 256 * i];
  }
  const int lane = t & 63, w = t >> 6;
  const int lo = lane & 15, hi = lane >> 4;
  f32x4 acc[2][8] = {};
  for (int kc = 0; kc < 2; ++kc) {
    if (kc) __syncthreads();
    {
      const int r = t >> 1, c4 = t & 1;
      const __hip_bfloat16* src = PQT + (size_t)(b * 256 + n0 + r) * KTOT + kc * 160;
      #pragma unroll
      for (int i = 0; i < 10; ++i) {
        int cc = c4 + 2 * i;
        *(short8*)&pan[r * 168 + cc * 8] = *(const short8*)(src + cc * 8);
      }
    }
    __syncthreads();
    #pragma unroll
    for (int kt2 = 0; kt2 < 5; ++kt2) {
      const int kt = kc * 5 + kt2;
      short8 af[2], bf[8];
      #pragma unroll
      for (int rb = 0; rb < 2; ++rb) {
        int lu = w * 32 + rb * 16 + lo;
        unsigned m = mskL[lu * 10 + kt];
        unsigned by = (m >> (hi * 8)) & 0xFFu;
        union { unsigned u[4]; short8 s; } cv;
        cv.u[0] = ((by & 1u)  ? 0x3F80u : 0u) | ((by & 2u)   ? 0x3F800000u : 0u);
        cv.u[1] = ((by & 4u)  ? 0x3F80u : 0u) | ((by & 8u)   ? 0x3F800000u : 0u);
        cv.u[2] = ((by & 16u) ? 0x3F80u : 0u) | ((by & 32u)  ? 0x3F800000u : 0u);
        cv.u[3] = ((by & 64u) ? 0x3F80u : 0u) | ((by & 128u) ? 0x3F800000u : 0u);
        af[rb] = cv.s;
      }
      #pragma unroll
      for (int cb = 0; cb < 8; ++cb) {
        int n = cb * 16 + lo;
        bf[cb] = *(const short8*)&pan[n * 168 + (kt2 * 4 + hi) * 8];
      }
      #pragma unroll
      for (int rb = 0; rb < 2; ++rb)
        #pragma unroll
        for (int cb = 0; cb < 8; ++cb)
          acc[rb][cb] = __builtin_amdgcn_mfma_f32_16x16x32_bf16(af[rb], bf[cb], acc[rb][cb], 0, 0, 0);
    }
  }
  #pragma unroll
  for (int cb = 0; cb < 8; ++cb) {
    int n = cb * 16 + lo;
    float bv = b1[n0 + n];
    #pragma unroll
    for (int rb = 0; rb < 2; ++rb) {
      #pragma unroll
      for (int j = 0; j < 4; ++j) {
        int u = b * 256 + uh * 128 + w * 32 + rb * 16 + hi * 4 + j;
        h1[(size_t)u * HD + n0 + n] = f2b(fmaxf(acc[rb][cb][j] + bv, 0.f));
      }
    }
  }
}

// ---------------------------------------------------------------------------
// K4: layer-2 GEMM + heads, M-tile 64 users. grid (256, 2).
// As 64x256 swizzled (32 KB); Bs per-ks [256][72] (36 KB). acc [4][4].
// sel-GEMM uses all 4 waves (16 users each).
// ---------------------------------------------------------------------------
__global__ __launch_bounds__(256) void k_heads(
    const __hip_bfloat16* __restrict__ h1o, const __hip_bfloat16* __restrict__ h1s,
    const __hip_bfloat16* __restrict__ W2T_o, const __hip_bfloat16* __restrict__ W2T_s,
    const float* __restrict__ ob2, const float* __restrict__ sb2,
    const float* __restrict__ oW3, const float* __restrict__ ob3,
    const __hip_bfloat16* __restrict__ W3T_s, const float* __restrict__ sb3,
    const unsigned long long* __restrict__ connS,
    float* __restrict__ out) {
  const int mlp = blockIdx.y;
  const int x = blockIdx.x;
  const int blk = (x & 7) * 32 + (x >> 3);      // XCD-affine, bijective (256%8==0)
  const int u0 = blk * 64;
  const int t = threadIdx.x, lane = t & 63, wid = t >> 6;
  const int lo = lane & 15, hi = lane >> 4;

  const __hip_bfloat16* A   = mlp ? h1s : h1o;
  const __hip_bfloat16* W2T = mlp ? W2T_s : W2T_o;
  const float* b2 = mlp ? sb2 : ob2;

  __shared__ __align__(16) char lds[32768 + 36864];
  short* As = (short*)lds;               // 64 x 256 swizzled, reused as sel
  short* Bs = (short*)(lds + 32768);     // 256 x 72 padded rows
  float* part = (float*)lds;             // alias (mlp==0, after barrier)

  // stage A tile (2048 chunks)
  #pragma unroll
  for (int i = 0; i < 8; ++i) {
    int c = t + i * 256;
    int row = c >> 5, cc = c & 31;
    *(short8*)&As[row * 256 + (cc ^ (row & 7)) * 8] =
        *(const short8*)(A + (size_t)(u0 + row) * HD + cc * 8);
  }
  __syncthreads();

  f32x4 acc2[4][4] = {};
  for (int ks = 0; ks < 8; ++ks) {
    if (ks) __syncthreads();
    #pragma unroll
    for (int i = 0; i < 4; ++i) {        // stage Bs: 1024 chunks
      int c = t + i * 256;
      int n = c >> 2, kc = c & 3;
      *(short8*)&Bs[n * 72 + kc * 8] =
          *(const short8*)(W2T + (size_t)n * HD + ks * 32 + kc * 8);
    }
    __syncthreads();
    short8 af[4], bf[4];
    #pragma unroll
    for (int rb = 0; rb < 4; ++rb) {
      int row = rb * 16 + lo;
      int ca = ks * 4 + hi;
      af[rb] = *(const short8*)&As[row * 256 + (ca ^ (row & 7)) * 8];
    }
    #pragma unroll
    for (int cb = 0; cb < 4; ++cb) {
      int n = wid * 64 + cb * 16 + lo;
      bf[cb] = *(const short8*)&Bs[n * 72 + hi * 8];
    }
    #pragma unroll
    for (int rb = 0; rb < 4; ++rb)
      #pragma unroll
      for (int cb = 0; cb < 4; ++cb)
        acc2[rb][cb] = __builtin_amdgcn_mfma_f32_16x16x32_bf16(af[rb], bf[cb], acc2[rb][cb], 0, 0, 0);
  }
  __syncthreads();                        // As reads done -> reuse as part/sel

  if (mlp == 0) {
    float p0[4][4] = {}, p1[4][4] = {};
    #pragma unroll
    for (int cb = 0; cb < 4; ++cb) {
      int n = wid * 64 + cb * 16 + lo;
      float bs = b2[n], w0 = oW3[2 * n], w1 = oW3[2 * n + 1];
      #pragma unroll
      for (int rb = 0; rb < 4; ++rb)
        #pragma unroll
        for (int j = 0; j < 4; ++j) {
          float sig = 1.0f / (1.0f + __expf(-(acc2[rb][cb][j] + bs)));
          p0[rb][j] = fmaf(sig, w0, p0[rb][j]);
          p1[rb][j] = fmaf(sig, w1, p1[rb][j]);
        }
    }
    #pragma unroll
    for (int rb = 0; rb < 4; ++rb)
      #pragma unroll
      for (int j = 0; j < 4; ++j) {
        #pragma unroll
        for (int off = 1; off < 16; off <<= 1) {
          p0[rb][j] += __shfl_xor(p0[rb][j], off, 64);
          p1[rb][j] += __shfl_xor(p1[rb][j], off, 64);
        }
        if (lo == 0) {
          int row = rb * 16 + hi * 4 + j;
          part[wid * 128 + row * 2 + 0] = p0[rb][j];
          part[wid * 128 + row * 2 + 1] = p1[rb][j];
        }
      }
    __syncthreads();
    if (t < 64) {
      float q0 = part[t * 2] + part[128 + t * 2] + part[256 + t * 2] + part[384 + t * 2] + ob3[0];
      float q1 = part[t * 2 + 1] + part[128 + t * 2 + 1] + part[256 + t * 2 + 1] + part[384 + t * 2 + 1] + ob3[1];
      float m2 = fmaxf(q0, q1);
      float e0 = __expf(q0 - m2), e1 = __expf(q1 - m2);
      float iv = 1.0f / (e0 + e1);
      float2 r; r.x = e0 * iv; r.y = e1 * iv;
      *(float2*)(out + (size_t)(u0 + t) * 2) = r;
    }
  } else {
    short* sel = As;
    #pragma unroll
    for (int cb = 0; cb < 4; ++cb) {
      int n = wid * 64 + cb * 16 + lo;
      float bs = b2[n];
      #pragma unroll
      for (int rb = 0; rb < 4; ++rb)
        #pragma unroll
        for (int j = 0; j < 4; ++j) {
          int row = rb * 16 + hi * 4 + j;
          float sig = 1.0f / (1.0f + __expf(-(acc2[rb][cb][j] + bs)));
          sel[row * 256 + ((n >> 3) ^ (row & 7)) * 8 + (n & 7)] = (short)pack2(sig, 0.f);
        }
    }
    __syncthreads();
    // sel GEMM: all 4 waves, 16 users each, 64 slots (B = W3T from L2)
    f32x4 acc3[4] = {};
    #pragma unroll
    for (int ks = 0; ks < 8; ++ks) {
      int row = wid * 16 + lo;
      int ca = ks * 4 + hi;
      short8 af = *(const short8*)&sel[row * 256 + (ca ^ (row & 7)) * 8];
      #pragma unroll
      for (int cb = 0; cb < 4; ++cb) {
        short8 bf = *(const short8*)(W3T_s + (size_t)(cb * 16 + lo) * HD + ks * 32 + hi * 8);
        acc3[cb] = __builtin_amdgcn_mfma_f32_16x16x32_bf16(af, bf, acc3[cb], 0, 0, 0);
      }
    }
    float sb3n[4];
    #pragma unroll
    for (int cb = 0; cb < 4; ++cb) sb3n[cb] = sb3[cb * 16 + lo];
    const int ubase = u0 + wid * 16 + hi * 4;
    #pragma unroll
    for (int j = 0; j < 4; ++j) {
      unsigned long long m = connS[ubase + j];
      float v[4]; bool ok[4];
      float mx = -INFINITY;
      #pragma unroll
      for (int cb = 0; cb < 4; ++cb) {
        int n = cb * 16 + lo;
        ok[cb] = (m >> n) & 1ull;
        v[cb] = ok[cb] ? (acc3[cb][j] + sb3n[cb]) : -INFINITY;
        mx = fmaxf(mx, v[cb]);
      }
      #pragma unroll
      for (int off = 1; off < 16; off <<= 1) mx = fmaxf(mx, __shfl_xor(mx, off, 64));
      float e[4], ssum = 0.f;
      #pragma unroll
      for (int cb = 0; cb < 4; ++cb) {
        e[cb] = ok[cb] ? __expf(v[cb] - mx) : 0.f;
        ssum += e[cb];
      }
      #pragma unroll
      for (int off = 1; off < 16; off <<= 1) ssum += __shfl_xor(ssum, off, 64);
      float iv = 1.0f / ssum;
      #pragma unroll
      for (int cb = 0; cb < 4; ++cb) {
        int n = cb * 16 + lo;
        out[(size_t)NUSER * 2 + (size_t)(ubase + j) * SSLOT + n] = e[cb] * iv;
      }
    }
  }
}

// ---------------------------------------------------------------------------
extern "C" void kernel_launch(void* const* d_in, const int* in_sizes, int n_in,
                              void* d_out, int out_size, void* d_ws, size_t ws_size,
                              hipStream_t stream) {
  const float* x_user   = (const float*)d_in[0];
  const float* x_server = (const float*)d_in[1];
  const int*   dst_u2s  = (const int*)d_in[3];
  const int*   dst_u2u  = (const int*)d_in[5];
  const float* oW1 = (const float*)d_in[6];
  const float* ob1 = (const float*)d_in[7];
  const float* oW2 = (const float*)d_in[8];
  const float* ob2 = (const float*)d_in[9];
  const float* oW3 = (const float*)d_in[10];
  const float* ob3 = (const float*)d_in[11];
  const float* sW1 = (const float*)d_in[12];
  const float* sb1 = (const float*)d_in[13];
  const float* sW2 = (const float*)d_in[14];
  const float* sb2 = (const float*)d_in[15];
  const float* sW3 = (const float*)d_in[16];
  const float* sb3 = (const float*)d_in[17];

  char* ws = (char*)d_ws;
  unsigned long long* connS = (unsigned long long*)(ws + 0);         // 128 KB
  unsigned*       MSUW  = (unsigned*)(ws + 131072);                  // 640 KB
  __hip_bfloat16* P_o  = (__hip_bfloat16*)(ws + 786432);             // 2 MB
  __hip_bfloat16* P_s  = (__hip_bfloat16*)(ws + 2883584);            // 2 MB
  __hip_bfloat16* Q_o  = (__hip_bfloat16*)(ws + 4980736);            // 8 MB
  __hip_bfloat16* Q_s  = (__hip_bfloat16*)(ws + 13369344);           // 8 MB
  __hip_bfloat16* PQT_o = (__hip_bfloat16*)(ws + 21757952);          // 10 MB
  __hip_bfloat16* PQT_s = (__hip_bfloat16*)(ws + 32243712);          // 10 MB
  __hip_bfloat16* h1o  = (__hip_bfloat16*)(ws + 42729472);           // 8 MB
  __hip_bfloat16* h1s  = (__hip_bfloat16*)(ws + 51118080);           // 8 MB
  __hip_bfloat16* W2T_o = (__hip_bfloat16*)(ws + 59506688);          // 128 KB
  __hip_bfloat16* W2T_s = (__hip_bfloat16*)(ws + 59637760);          // 128 KB
  __hip_bfloat16* W3T_s = (__hip_bfloat16*)(ws + 59768832);          // 32 KB
  float* out = (float*)d_out;

  k_prep_pq<<<dim3(320, 9), 256, 0, stream>>>(
      dst_u2s, dst_u2u, oW2, sW2, sW3, x_user, x_server, oW1, sW1,
      connS, MSUW, W2T_o, W2T_s, W3T_s, P_o, P_s, Q_o, Q_s);
  k_tr<<<dim3(64, 2, 4), 256, 0, stream>>>(P_o, P_s, Q_o, Q_s, PQT_o, PQT_s);
  k_h1<<<dim3(128, 2, 2), 256, 0, stream>>>(MSUW, PQT_o, PQT_s, ob1, sb1, h1o, h1s);
  k_heads<<<dim3(256, 2), 256, 0, stream>>>(h1o, h1s, W2T_o, W2T_s, ob2, sb2,
                                            oW3, ob3, W3T_s, sb3, connS, out);
}

// Round 15
// 56.812 us; speedup vs baseline: 4.4034x; 1.0212x over previous
//
#include <hip/hip_runtime.h>
#include <hip/hip_bf16.h>
#include <math.h>
#include <cstdint>

#define NUSER 16384   // B*U
#define BB    64
#define UU    256
#define SSLOT 64
#define HD    256
#define KTOT  320
#define DEGS  8
#define DEGU  16

typedef __attribute__((ext_vector_type(8))) short short8;
typedef __attribute__((ext_vector_type(4))) float f32x4;

static __device__ __forceinline__ __hip_bfloat16 f2b(float x) { return __float2bfloat16(x); }
static __device__ __forceinline__ unsigned pack2(float x, float y) {
  union { __hip_bfloat16 h[2]; unsigned u; } cv;
  cv.h[0] = f2b(x); cv.h[1] = f2b(y);
  return cv.u;
}

// ---------------------------------------------------------------------------
// K1: merged prep + per-slot layer-1 products.
// y==0, x<64 : connS + mask words + W3F fragment-pack (n = x).
// y==0, x>=64: W2F fragment-pack (n = x-64).
// y>=1       : pq body (round-9 verbatim), 8 batches per block.
// Fragment layout: WF[((nblk*8+ks)*64 + lane)*8 + e] = W[k][n],
//   n = nblk*16 + (lane&15), k = ks*32 + (lane>>4)*8 + e.
// ---------------------------------------------------------------------------
__global__ __launch_bounds__(256) void k_prep_pq(
    const int* __restrict__ dst_u2s, const int* __restrict__ dst_u2u,
    const float* __restrict__ oW2, const float* __restrict__ sW2,
    const float* __restrict__ sW3,
    const float* __restrict__ xu, const float* __restrict__ xs,
    const float* __restrict__ oW1, const float* __restrict__ sW1,
    unsigned long long* __restrict__ connS, unsigned* __restrict__ MSUW,
    __hip_bfloat16* __restrict__ W2F_o, __hip_bfloat16* __restrict__ W2F_s,
    __hip_bfloat16* __restrict__ W3F_s,
    __hip_bfloat16* __restrict__ P_o, __hip_bfloat16* __restrict__ P_s,
    __hip_bfloat16* __restrict__ Q_o, __hip_bfloat16* __restrict__ Q_s) {
  const int t = threadIdx.x;
  if (blockIdx.y == 0) {
    const int blk = blockIdx.x;
    if (blk < 64) {
      const int u = blk * 256 + t;
      unsigned long long ms = 0ull;
      #pragma unroll
      for (int i = 0; i < DEGS; ++i) ms |= 1ull << (dst_u2s[u * DEGS + i] & 63);
      connS[u] = ms;
      unsigned long long m0 = 0, m1 = 0, m2 = 0, m3 = 0;
      #pragma unroll
      for (int i = 0; i < DEGU; ++i) {
        int slot = dst_u2u[u * DEGU + i] & 255;
        unsigned long long bit = 1ull << (slot & 63);
        int w = slot >> 6;
        if (w == 0) m0 |= bit; else if (w == 1) m1 |= bit;
        else if (w == 2) m2 |= bit; else m3 |= bit;
      }
      unsigned* mw = MSUW + (size_t)u * 10;
      uint2* mw2 = (uint2*)mw;
      mw2[0] = make_uint2((unsigned)ms, (unsigned)(ms >> 32));
      mw2[1] = make_uint2((unsigned)m0, (unsigned)(m0 >> 32));
      mw2[2] = make_uint2((unsigned)m1, (unsigned)(m1 >> 32));
      mw2[3] = make_uint2((unsigned)m2, (unsigned)(m2 >> 32));
      mw2[4] = make_uint2((unsigned)m3, (unsigned)(m3 >> 32));
      // W3F pack: n = blk; thread t -> (ks, hi, e)
      {
        const int n = blk;
        const int ks = t >> 5, hi = (t >> 3) & 3, e = t & 7;
        const int lane = hi * 16 + (n & 15);
        const size_t idx = (size_t)((((n >> 4) * 8 + ks) * 64 + lane)) * 8 + e;
        W3F_s[idx] = f2b(sW3[(ks * 32 + hi * 8 + e) * SSLOT + n]);
      }
    } else {
      // W2F pack: n = blk - 64; thread t -> (ks, hi, e)
      const int n = blk - 64;
      const int ks = t >> 5, hi = (t >> 3) & 3, e = t & 7;
      const int lane = hi * 16 + (n & 15);
      const size_t idx = (size_t)((((n >> 4) * 8 + ks) * 64 + lane)) * 8 + e;
      const int k = ks * 32 + hi * 8 + e;
      W2F_o[idx] = f2b(oW2[k * HD + n]);
      W2F_s[idx] = f2b(sW2[k * HD + n]);
    }
    return;
  }
  // ---- pq body ----
  const int wg = blockIdx.x;
  const int b0 = (blockIdx.y - 1) * 8;
  __shared__ float lx[8 * 16];
  const bool isS = wg < SSLOT;
  const int slot = isS ? wg : wg - SSLOT;
  if (t < 8 * 16) {
    int b = b0 + (t >> 4), d = t & 15;
    lx[t] = isS ? xs[(b * SSLOT + slot) * 16 + d] : xu[(b * UU + slot) * 16 + d];
  }
  __syncthreads();
  float wo[16], wsv[16];
  const int rbase = isS ? slot * 16 : SSLOT * 16 + slot * 16;
  #pragma unroll
  for (int d = 0; d < 16; ++d) {
    wo[d] = oW1[(rbase + d) * HD + t];
    wsv[d] = sW1[(rbase + d) * HD + t];
  }
  __hip_bfloat16* Ro = isS ? P_o : Q_o;
  __hip_bfloat16* Rs = isS ? P_s : Q_s;
  const int rows = isS ? SSLOT : UU;
  #pragma unroll
  for (int bi = 0; bi < 8; ++bi) {
    float ao = 0.f, as = 0.f;
    #pragma unroll
    for (int q = 0; q < 4; ++q) {
      float4 x4 = *(const float4*)&lx[bi * 16 + q * 4];
      ao = fmaf(x4.x, wo[q*4+0], ao); as = fmaf(x4.x, wsv[q*4+0], as);
      ao = fmaf(x4.y, wo[q*4+1], ao); as = fmaf(x4.y, wsv[q*4+1], as);
      ao = fmaf(x4.z, wo[q*4+2], ao); as = fmaf(x4.z, wsv[q*4+2], as);
      ao = fmaf(x4.w, wo[q*4+3], ao); as = fmaf(x4.w, wsv[q*4+3], as);
    }
    Ro[((b0 + bi) * rows + slot) * HD + t] = f2b(ao);
    Rs[((b0 + bi) * rows + slot) * HD + t] = f2b(as);
  }
}

// ---------------------------------------------------------------------------
// K2 (round-9 verbatim): transpose P,Q -> PQT[b][n][320] via LDS.
// ---------------------------------------------------------------------------
__global__ __launch_bounds__(256) void k_tr(
    const __hip_bfloat16* __restrict__ P_o, const __hip_bfloat16* __restrict__ P_s,
    const __hip_bfloat16* __restrict__ Q_o, const __hip_bfloat16* __restrict__ Q_s,
    __hip_bfloat16* __restrict__ PQT_o, __hip_bfloat16* __restrict__ PQT_s) {
  const int b = blockIdx.x, mlp = blockIdx.y, nc = blockIdx.z;
  const int n0 = nc * 64;
  const int t = threadIdx.x;
  const __hip_bfloat16* P = mlp ? P_s : P_o;
  const __hip_bfloat16* Q = mlp ? Q_s : Q_o;
  __hip_bfloat16* PQT = mlp ? PQT_s : PQT_o;
  __shared__ __align__(16) short lds[64 * 72];
  for (int kt = 0; kt < 5; ++kt) {
    const __hip_bfloat16* src = (kt == 0) ? (P + (size_t)(b * SSLOT) * HD)
                                          : (Q + (size_t)(b * UU + (kt - 1) * 64) * HD);
    const int kout = (kt == 0) ? 0 : 64 + (kt - 1) * 64;
    #pragma unroll
    for (int i = 0; i < 2; ++i) {
      int c = t + i * 256;
      int row = c >> 3, cc = c & 7;
      *(short8*)&lds[row * 72 + cc * 8] =
          *(const short8*)(src + (size_t)row * HD + n0 + cc * 8);
    }
    __syncthreads();
    #pragma unroll
    for (int i = 0; i < 2; ++i) {
      int c = t + i * 256;
      int nrow = c >> 3, kc = c & 7;
      short8 v;
      #pragma unroll
      for (int e = 0; e < 8; ++e) v[e] = lds[(kc * 8 + e) * 72 + nrow];
      *(short8*)(PQT + (size_t)(b * 256 + n0 + nrow) * KTOT + kout + kc * 8) = v;
    }
    __syncthreads();
  }
}

// ---------------------------------------------------------------------------
// K3 (round-13 verbatim): h1 via mask-MFMA, k-chunked 48 KB LDS.
// ---------------------------------------------------------------------------
__global__ __launch_bounds__(256) void k_h1(
    const unsigned* __restrict__ MSUW,
    const __hip_bfloat16* __restrict__ PQT_o, const __hip_bfloat16* __restrict__ PQT_s,
    const float* __restrict__ ob1, const float* __restrict__ sb1,
    __hip_bfloat16* __restrict__ h1o, __hip_bfloat16* __restrict__ h1s) {
  const int b = blockIdx.x >> 1, uh = blockIdx.x & 1;
  const int mlp = blockIdx.y, nh = blockIdx.z;
  const int n0 = nh * 128;
  const int t = threadIdx.x;
  const __hip_bfloat16* PQT = mlp ? PQT_s : PQT_o;
  const float* b1 = mlp ? sb1 : ob1;
  __hip_bfloat16* h1 = mlp ? h1s : h1o;

  __shared__ __align__(16) char smem[48128];
  short* pan = (short*)smem;                   // [128][168]
  unsigned* mskL = (unsigned*)(smem + 43008);  // 1280 u32

  {
    const unsigned* g = MSUW + (size_t)(b * 256 + uh * 128) * 10;
    #pragma unroll
    for (int i = 0; i < 5; ++i) mskL[t + 256 * i] = g[t + 256 * i];
  }
  const int lane = t & 63, w = t >> 6;
  const int lo = lane & 15, hi = lane >> 4;
  f32x4 acc[2][8] = {};
  for (int kc = 0; kc < 2; ++kc) {
    if (kc) __syncthreads();
    {
      const int r = t >> 1, c4 = t & 1;
      const __hip_bfloat16* src = PQT + (size_t)(b * 256 + n0 + r) * KTOT + kc * 160;
      #pragma unroll
      for (int i = 0; i < 10; ++i) {
        int cc = c4 + 2 * i;
        *(short8*)&pan[r * 168 + cc * 8] = *(const short8*)(src + cc * 8);
      }
    }
    __syncthreads();
    #pragma unroll
    for (int kt2 = 0; kt2 < 5; ++kt2) {
      const int kt = kc * 5 + kt2;
      short8 af[2], bf[8];
      #pragma unroll
      for (int rb = 0; rb < 2; ++rb) {
        int lu = w * 32 + rb * 16 + lo;
        unsigned m = mskL[lu * 10 + kt];
        unsigned by = (m >> (hi * 8)) & 0xFFu;
        union { unsigned u[4]; short8 s; } cv;
        cv.u[0] = ((by & 1u)  ? 0x3F80u : 0u) | ((by & 2u)   ? 0x3F800000u : 0u);
        cv.u[1] = ((by & 4u)  ? 0x3F80u : 0u) | ((by & 8u)   ? 0x3F800000u : 0u);
        cv.u[2] = ((by & 16u) ? 0x3F80u : 0u) | ((by & 32u)  ? 0x3F800000u : 0u);
        cv.u[3] = ((by & 64u) ? 0x3F80u : 0u) | ((by & 128u) ? 0x3F800000u : 0u);
        af[rb] = cv.s;
      }
      #pragma unroll
      for (int cb = 0; cb < 8; ++cb) {
        int n = cb * 16 + lo;
        bf[cb] = *(const short8*)&pan[n * 168 + (kt2 * 4 + hi) * 8];
      }
      #pragma unroll
      for (int rb = 0; rb < 2; ++rb)
        #pragma unroll
        for (int cb = 0; cb < 8; ++cb)
          acc[rb][cb] = __builtin_amdgcn_mfma_f32_16x16x32_bf16(af[rb], bf[cb], acc[rb][cb], 0, 0, 0);
    }
  }
  #pragma unroll
  for (int cb = 0; cb < 8; ++cb) {
    int n = cb * 16 + lo;
    float bv = b1[n0 + n];
    #pragma unroll
    for (int rb = 0; rb < 2; ++rb) {
      #pragma unroll
      for (int j = 0; j < 4; ++j) {
        int u = b * 256 + uh * 128 + w * 32 + rb * 16 + hi * 4 + j;
        h1[(size_t)u * HD + n0 + n] = f2b(fmaxf(acc[rb][cb][j] + bv, 0.f));
      }
    }
  }
}

// ---------------------------------------------------------------------------
// K4: layer-2 GEMM + heads, M-tile 64, fragment-packed B (no Bs staging,
// no k-loop barriers). grid (256, 2). LDS 34 KB -> 4 blocks/CU.
// ---------------------------------------------------------------------------
__global__ __launch_bounds__(256) void k_heads(
    const __hip_bfloat16* __restrict__ h1o, const __hip_bfloat16* __restrict__ h1s,
    const __hip_bfloat16* __restrict__ W2F_o, const __hip_bfloat16* __restrict__ W2F_s,
    const float* __restrict__ ob2, const float* __restrict__ sb2,
    const float* __restrict__ oW3, const float* __restrict__ ob3,
    const __hip_bfloat16* __restrict__ W3F_s, const float* __restrict__ sb3,
    const unsigned long long* __restrict__ connS,
    float* __restrict__ out) {
  const int mlp = blockIdx.y;
  const int x = blockIdx.x;
  const int blk = (x & 7) * 32 + (x >> 3);      // XCD-affine, bijective
  const int u0 = blk * 64;
  const int t = threadIdx.x, lane = t & 63, wid = t >> 6;
  const int lo = lane & 15, hi = lane >> 4;

  const __hip_bfloat16* A   = mlp ? h1s : h1o;
  const __hip_bfloat16* W2F = mlp ? W2F_s : W2F_o;
  const float* b2 = mlp ? sb2 : ob2;

  __shared__ __align__(16) char lds[32768 + 2048];
  short* As = (short*)lds;               // 64 x 256 swizzled, reused as sel
  float* part = (float*)(lds + 32768);   // [4][64][2] (mlp==0)

  // stage A tile (2048 chunks)
  #pragma unroll
  for (int i = 0; i < 8; ++i) {
    int c = t + i * 256;
    int row = c >> 5, cc = c & 31;
    *(short8*)&As[row * 256 + (cc ^ (row & 7)) * 8] =
        *(const short8*)(A + (size_t)(u0 + row) * HD + cc * 8);
  }
  __syncthreads();

  f32x4 acc2[4][4] = {};
  #pragma unroll
  for (int ks = 0; ks < 8; ++ks) {
    short8 af[4], bf[4];
    #pragma unroll
    for (int rb = 0; rb < 4; ++rb) {
      int row = rb * 16 + lo;
      int ca = ks * 4 + hi;
      af[rb] = *(const short8*)&As[row * 256 + (ca ^ (row & 7)) * 8];
    }
    #pragma unroll
    for (int cb = 0; cb < 4; ++cb) {
      bf[cb] = *(const short8*)(W2F + (size_t)((((wid * 4 + cb) * 8 + ks) * 64 + lane)) * 8);
    }
    #pragma unroll
    for (int rb = 0; rb < 4; ++rb)
      #pragma unroll
      for (int cb = 0; cb < 4; ++cb)
        acc2[rb][cb] = __builtin_amdgcn_mfma_f32_16x16x32_bf16(af[rb], bf[cb], acc2[rb][cb], 0, 0, 0);
  }
  __syncthreads();                        // As reads done -> reuse as sel

  if (mlp == 0) {
    float p0[4][4] = {}, p1[4][4] = {};
    #pragma unroll
    for (int cb = 0; cb < 4; ++cb) {
      int n = wid * 64 + cb * 16 + lo;
      float bs = b2[n], w0 = oW3[2 * n], w1 = oW3[2 * n + 1];
      #pragma unroll
      for (int rb = 0; rb < 4; ++rb)
        #pragma unroll
        for (int j = 0; j < 4; ++j) {
          float sig = 1.0f / (1.0f + __expf(-(acc2[rb][cb][j] + bs)));
          p0[rb][j] = fmaf(sig, w0, p0[rb][j]);
          p1[rb][j] = fmaf(sig, w1, p1[rb][j]);
        }
    }
    #pragma unroll
    for (int rb = 0; rb < 4; ++rb)
      #pragma unroll
      for (int j = 0; j < 4; ++j) {
        #pragma unroll
        for (int off = 1; off < 16; off <<= 1) {
          p0[rb][j] += __shfl_xor(p0[rb][j], off, 64);
          p1[rb][j] += __shfl_xor(p1[rb][j], off, 64);
        }
        if (lo == 0) {
          int row = rb * 16 + hi * 4 + j;
          part[wid * 128 + row * 2 + 0] = p0[rb][j];
          part[wid * 128 + row * 2 + 1] = p1[rb][j];
        }
      }
    __syncthreads();
    if (t < 64) {
      float q0 = part[t * 2] + part[128 + t * 2] + part[256 + t * 2] + part[384 + t * 2] + ob3[0];
      float q1 = part[t * 2 + 1] + part[128 + t * 2 + 1] + part[256 + t * 2 + 1] + part[384 + t * 2 + 1] + ob3[1];
      float m2 = fmaxf(q0, q1);
      float e0 = __expf(q0 - m2), e1 = __expf(q1 - m2);
      float iv = 1.0f / (e0 + e1);
      float2 r; r.x = e0 * iv; r.y = e1 * iv;
      *(float2*)(out + (size_t)(u0 + t) * 2) = r;
    }
  } else {
    short* sel = As;
    #pragma unroll
    for (int cb = 0; cb < 4; ++cb) {
      int n = wid * 64 + cb * 16 + lo;
      float bs = b2[n];
      #pragma unroll
      for (int rb = 0; rb < 4; ++rb)
        #pragma unroll
        for (int j = 0; j < 4; ++j) {
          int row = rb * 16 + hi * 4 + j;
          float sig = 1.0f / (1.0f + __expf(-(acc2[rb][cb][j] + bs)));
          sel[row * 256 + ((n >> 3) ^ (row & 7)) * 8 + (n & 7)] = (short)pack2(sig, 0.f);
        }
    }
    __syncthreads();
    // sel GEMM: all 4 waves, 16 users each, 64 slots (B = W3F from L2)
    f32x4 acc3[4] = {};
    #pragma unroll
    for (int ks = 0; ks < 8; ++ks) {
      int row = wid * 16 + lo;
      int ca = ks * 4 + hi;
      short8 af = *(const short8*)&sel[row * 256 + (ca ^ (row & 7)) * 8];
      #pragma unroll
      for (int cb = 0; cb < 4; ++cb) {
        short8 bf = *(const short8*)(W3F_s + (size_t)(((cb * 8 + ks) * 64 + lane)) * 8);
        acc3[cb] = __builtin_amdgcn_mfma_f32_16x16x32_bf16(af, bf, acc3[cb], 0, 0, 0);
      }
    }
    float sb3n[4];
    #pragma unroll
    for (int cb = 0; cb < 4; ++cb) sb3n[cb] = sb3[cb * 16 + lo];
    const int ubase = u0 + wid * 16 + hi * 4;
    #pragma unroll
    for (int j = 0; j < 4; ++j) {
      unsigned long long m = connS[ubase + j];
      float v[4]; bool ok[4];
      float mx = -INFINITY;
      #pragma unroll
      for (int cb = 0; cb < 4; ++cb) {
        int n = cb * 16 + lo;
        ok[cb] = (m >> n) & 1ull;
        v[cb] = ok[cb] ? (acc3[cb][j] + sb3n[cb]) : -INFINITY;
        mx = fmaxf(mx, v[cb]);
      }
      #pragma unroll
      for (int off = 1; off < 16; off <<= 1) mx = fmaxf(mx, __shfl_xor(mx, off, 64));
      float e[4], ssum = 0.f;
      #pragma unroll
      for (int cb = 0; cb < 4; ++cb) {
        e[cb] = ok[cb] ? __expf(v[cb] - mx) : 0.f;
        ssum += e[cb];
      }
      #pragma unroll
      for (int off = 1; off < 16; off <<= 1) ssum += __shfl_xor(ssum, off, 64);
      float iv = 1.0f / ssum;
      #pragma unroll
      for (int cb = 0; cb < 4; ++cb) {
        int n = cb * 16 + lo;
        out[(size_t)NUSER * 2 + (size_t)(ubase + j) * SSLOT + n] = e[cb] * iv;
      }
    }
  }
}

// ---------------------------------------------------------------------------
extern "C" void kernel_launch(void* const* d_in, const int* in_sizes, int n_in,
                              void* d_out, int out_size, void* d_ws, size_t ws_size,
                              hipStream_t stream) {
  const float* x_user   = (const float*)d_in[0];
  const float* x_server = (const float*)d_in[1];
  const int*   dst_u2s  = (const int*)d_in[3];
  const int*   dst_u2u  = (const int*)d_in[5];
  const float* oW1 = (const float*)d_in[6];
  const float* ob1 = (const float*)d_in[7];
  const float* oW2 = (const float*)d_in[8];
  const float* ob2 = (const float*)d_in[9];
  const float* oW3 = (const float*)d_in[10];
  const float* ob3 = (const float*)d_in[11];
  const float* sW1 = (const float*)d_in[12];
  const float* sb1 = (const float*)d_in[13];
  const float* sW2 = (const float*)d_in[14];
  const float* sb2 = (const float*)d_in[15];
  const float* sW3 = (const float*)d_in[16];
  const float* sb3 = (const float*)d_in[17];

  char* ws = (char*)d_ws;
  unsigned long long* connS = (unsigned long long*)(ws + 0);         // 128 KB
  unsigned*       MSUW  = (unsigned*)(ws + 131072);                  // 640 KB
  __hip_bfloat16* P_o  = (__hip_bfloat16*)(ws + 786432);             // 2 MB
  __hip_bfloat16* P_s  = (__hip_bfloat16*)(ws + 2883584);            // 2 MB
  __hip_bfloat16* Q_o  = (__hip_bfloat16*)(ws + 4980736);            // 8 MB
  __hip_bfloat16* Q_s  = (__hip_bfloat16*)(ws + 13369344);           // 8 MB
  __hip_bfloat16* PQT_o = (__hip_bfloat16*)(ws + 21757952);          // 10 MB
  __hip_bfloat16* PQT_s = (__hip_bfloat16*)(ws + 32243712);          // 10 MB
  __hip_bfloat16* h1o  = (__hip_bfloat16*)(ws + 42729472);           // 8 MB
  __hip_bfloat16* h1s  = (__hip_bfloat16*)(ws + 51118080);           // 8 MB
  __hip_bfloat16* W2F_o = (__hip_bfloat16*)(ws + 59506688);          // 128 KB
  __hip_bfloat16* W2F_s = (__hip_bfloat16*)(ws + 59637760);          // 128 KB
  __hip_bfloat16* W3F_s = (__hip_bfloat16*)(ws + 59768832);          // 32 KB
  float* out = (float*)d_out;

  k_prep_pq<<<dim3(320, 9), 256, 0, stream>>>(
      dst_u2s, dst_u2u, oW2, sW2, sW3, x_user, x_server, oW1, sW1,
      connS, MSUW, W2F_o, W2F_s, W3F_s, P_o, P_s, Q_o, Q_s);
  k_tr<<<dim3(64, 2, 4), 256, 0, stream>>>(P_o, P_s, Q_o, Q_s, PQT_o, PQT_s);
  k_h1<<<dim3(128, 2, 2), 256, 0, stream>>>(MSUW, PQT_o, PQT_s, ob1, sb1, h1o, h1s);
  k_heads<<<dim3(256, 2), 256, 0, stream>>>(h1o, h1s, W2F_o, W2F_s, ob2, sb2,
                                            oW3, ob3, W3F_s, sb3, connS, out);
}